// Round 2
// baseline (1393.902 us; speedup 1.0000x reference)
//
#include <hip/hip_runtime.h>
#include <stdint.h>

typedef unsigned short u16;
typedef __attribute__((ext_vector_type(8))) short short8;
typedef __attribute__((ext_vector_type(4))) float floatx4;

#define RS66  (66*128)
#define IS66  (66*66*128)
#define RS130 (130*128)
#define IS130 (130*130*128)

__device__ __forceinline__ float bf2f(u16 h) {
  union { unsigned u; float f; } v; v.u = ((unsigned)h) << 16; return v.f;
}
__device__ __forceinline__ u16 f2bf(float f) {
  union { float f; unsigned u; } v; v.f = f;
  unsigned r = v.u + 0x7FFFu + ((v.u >> 16) & 1u);
  return (u16)(r >> 16);
}
__device__ __forceinline__ void gl_lds16(const void* g, void* l) {
  __builtin_amdgcn_global_load_lds(
      (const __attribute__((address_space(1))) void*)(uintptr_t)g,
      (__attribute__((address_space(3))) void*)(uintptr_t)l, 16, 0, 0);
}
__device__ __forceinline__ unsigned fkey(float f) {
  unsigned u = __float_as_uint(f);
  return (u & 0x80000000u) ? ~u : (u | 0x80000000u);
}

struct Taps { int n; unsigned dh2; unsigned dw2; };  // 2-bit packed offsets, val-1 in {-1..2}

// ---------------- MFMA implicit-GEMM conv: tile 128 pixels x 128 outch, K=taps*128 ----------------
__global__ __launch_bounds__(256) void conv_mfma(
    const u16* __restrict__ in, int inRS, int inIS, int si,
    const u16* __restrict__ wt, const float* __restrict__ bias, Taps tp,
    u16* __restrict__ out, int outRS, int outIS, int so, int oh0, int ow0,
    const u16* __restrict__ res, u16* __restrict__ out2, int reluMain,
    float* __restrict__ zeOut, u16* __restrict__ zeBFc)
{
  __shared__ u16 lA[4096];
  __shared__ u16 lB[4096];
  const int tid = threadIdx.x;
  const int w = tid >> 6, lane = tid & 63, quad = lane >> 4, l16 = lane & 15;
  const int wm = w >> 1, wn = w & 1;
  const int q = tid & 3, p0 = tid >> 2;
  const int blockM = blockIdx.x << 7;
  const int pg0 = blockM + p0, pg1 = pg0 + 64;
  const int b0 = pg0 >> 12, mo0 = (pg0 >> 6) & 63, no0 = pg0 & 63;
  const int b1 = pg1 >> 12, mo1 = (pg1 >> 6) & 63, no1 = pg1 & 63;
  const u16* gA0 = in + b0*inIS + si*mo0*inRS + si*no0*128 + q*8;
  const u16* gA1 = in + b1*inIS + si*mo1*inRS + si*no1*128 + q*8;
  const u16* gB0 = wt + p0*128 + q*8;
  const u16* gB1 = gB0 + 64*128;
  u16* lsA0 = lA + w*512; u16* lsA1 = lsA0 + 2048;
  u16* lsB0 = lB + w*512; u16* lsB1 = lsB0 + 2048;

  floatx4 zz = {0.f,0.f,0.f,0.f};
  floatx4 acc[4][4];
#pragma unroll
  for (int i=0;i<4;i++)
#pragma unroll
    for (int j=0;j<4;j++) acc[i][j] = zz;

  for (int t = 0; t < tp.n; ++t) {
    const int dh = (int)((tp.dh2 >> (2*t)) & 3u) - 1;
    const int dw = (int)((tp.dw2 >> (2*t)) & 3u) - 1;
    const int aoff = dh*inRS + dw*128;
    const int boff = t << 14;
#pragma unroll
    for (int kc = 0; kc < 4; ++kc) {
      __syncthreads();
      gl_lds16(gA0 + aoff + kc*32, lsA0);
      gl_lds16(gA1 + aoff + kc*32, lsA1);
      gl_lds16(gB0 + boff + kc*32, lsB0);
      gl_lds16(gB1 + boff + kc*32, lsB1);
      __syncthreads();
      short8 af[4], bfr[4];
#pragma unroll
      for (int s=0;s<4;s++) af[s]  = *(const short8*)&lA[(wm*64 + s*16 + l16)*32 + quad*8];
#pragma unroll
      for (int s=0;s<4;s++) bfr[s] = *(const short8*)&lB[(wn*64 + s*16 + l16)*32 + quad*8];
#pragma unroll
      for (int i=0;i<4;i++)
#pragma unroll
        for (int j=0;j<4;j++)
          acc[i][j] = __builtin_amdgcn_mfma_f32_16x16x32_bf16(af[i], bfr[j], acc[i][j], 0, 0, 0);
    }
  }

  float bv[4];
#pragma unroll
  for (int j=0;j<4;j++) bv[j] = bias[wn*64 + j*16 + l16];

#pragma unroll
  for (int i=0;i<4;i++) {
#pragma unroll
    for (int r=0;r<4;r++) {
      const int p = blockM + wm*64 + i*16 + quad*4 + r;
      const int bb = p >> 12, mo = (p >> 6) & 63, no = p & 63;
      const int ob = bb*outIS + (so*mo + oh0)*outRS + (so*no + ow0)*128;
#pragma unroll
      for (int j=0;j<4;j++) {
        const int n = wn*64 + j*16 + l16;
        float v = acc[i][j][r] + bv[j];
        if (res)  v += bf2f(res[ob + n]);
        if (out)  out[ob + n]  = f2bf(reluMain ? fmaxf(v, 0.f) : v);
        if (out2) out2[ob + n] = f2bf(fmaxf(v, 0.f));
        if (zeOut) {
          zeOut[(((size_t)bb) << 19) + ((size_t)n << 12) + (p & 4095)] = v;  // NCHW fp32 direct
          zeBFc[((size_t)p << 7) + n] = f2bf(v);                             // compact for VQ
        }
      }
    }
  }
}

// ---------------- VQ: scores = ze . cb^T, per-pixel argmin via packed atomicMin ----------------
__global__ __launch_bounds__(256) void vq_score(
    const u16* __restrict__ zeBF, const u16* __restrict__ cbBF,
    const float* __restrict__ cbn, unsigned long long* __restrict__ minbuf)
{
  __shared__ u16 lA[4096];
  __shared__ u16 lB[4096];
  const int tid = threadIdx.x;
  const int w = tid >> 6, lane = tid & 63, quad = lane >> 4, l16 = lane & 15;
  const int wm = w >> 1, wn = w & 1;
  const int q = tid & 3, p0 = tid >> 2;
  const int blockM = blockIdx.x << 7;
  const int nb = blockIdx.y;
  const u16* gA0 = zeBF + ((blockM + p0) << 7) + q*8;
  const u16* gA1 = gA0 + (64 << 7);
  const u16* gB0 = cbBF + ((nb*128 + p0) << 7) + q*8;
  const u16* gB1 = gB0 + (64 << 7);
  u16* lsA0 = lA + w*512; u16* lsA1 = lsA0 + 2048;
  u16* lsB0 = lB + w*512; u16* lsB1 = lsB0 + 2048;

  floatx4 zz = {0.f,0.f,0.f,0.f};
  floatx4 acc[4][4];
#pragma unroll
  for (int i=0;i<4;i++)
#pragma unroll
    for (int j=0;j<4;j++) acc[i][j] = zz;

#pragma unroll
  for (int kc = 0; kc < 4; ++kc) {
    __syncthreads();
    gl_lds16(gA0 + kc*32, lsA0);
    gl_lds16(gA1 + kc*32, lsA1);
    gl_lds16(gB0 + kc*32, lsB0);
    gl_lds16(gB1 + kc*32, lsB1);
    __syncthreads();
    short8 af[4], bfr[4];
#pragma unroll
    for (int s=0;s<4;s++) af[s]  = *(const short8*)&lA[(wm*64 + s*16 + l16)*32 + quad*8];
#pragma unroll
    for (int s=0;s<4;s++) bfr[s] = *(const short8*)&lB[(wn*64 + s*16 + l16)*32 + quad*8];
#pragma unroll
    for (int i=0;i<4;i++)
#pragma unroll
      for (int j=0;j<4;j++)
        acc[i][j] = __builtin_amdgcn_mfma_f32_16x16x32_bf16(af[i], bfr[j], acc[i][j], 0, 0, 0);
  }

  float cn[4];
#pragma unroll
  for (int j=0;j<4;j++) cn[j] = cbn[nb*128 + wn*64 + j*16 + l16];

#pragma unroll
  for (int i=0;i<4;i++) {
#pragma unroll
    for (int r=0;r<4;r++) {
      const int p = blockM + wm*64 + i*16 + quad*4 + r;
      unsigned long long best = 0xFFFFFFFFFFFFFFFFull;
#pragma unroll
      for (int j=0;j<4;j++) {
        const int n = nb*128 + wn*64 + j*16 + l16;
        float v = cn[j] - acc[i][j][r];       // 0.5||e||^2 - z.e  (same argmin as L2 dist)
        unsigned long long pk = ((unsigned long long)fkey(v) << 32) | (unsigned)n;
        if (pk < best) best = pk;
      }
#pragma unroll
      for (int d=1; d<16; d<<=1) {
        unsigned long long o = __shfl_xor(best, d, 64);
        if (o < best) best = o;
      }
      if (l16 == 0) atomicMin(minbuf + p, best);
    }
  }
}

// ---------------- zq: gather codebook -> fp32 NCHW out + bf16 padded decoder input ----------------
__global__ __launch_bounds__(256) void zq_out_k(
    const unsigned long long* __restrict__ minb, const float* __restrict__ cb,
    float* __restrict__ outZ, u16* __restrict__ zqI)
{
  int id = blockIdx.x*256 + threadIdx.x;   // 16*4096*128
  int c = id & 127, p = id >> 7;
  int n = (int)(unsigned)(minb[p] & 0xFFFFFFFFull);
  float v = cb[(n << 7) + c];
  int b = p >> 12, hw = p & 4095;
  outZ[(((size_t)b) << 19) + ((size_t)c << 12) + hw] = v;   // NCHW (scattered; L2 merges)
  int h = hw >> 6, w2 = hw & 63;
  zqI[b*IS66 + h*RS66 + w2*128 + c] = f2bf(v);              // coalesced (interior)
}

// ---------------- zero halos + init VQ argmin buffer ----------------
__global__ __launch_bounds__(256) void zero_halos(
    u16* big, u16* s0, u16* s1, u16* s2, u16* s3, unsigned long long* minb)
{
  int id = blockIdx.x*256 + threadIdx.x;
  if (id >= 463872) return;
  if (id >= 398336) { minb[id - 398336] = 0xFFFFFFFFFFFFFFFFull; return; }
  u16* base; int H, W;
  if (id < 132096) { base = big; H = 128; W = 128; }
  else {
    id -= 132096;
    int bi = id / 66560;
    id -= bi*66560;
    base = (bi == 0) ? s0 : (bi == 1) ? s1 : (bi == 2) ? s2 : s3;
    H = 64; W = 64;
  }
  int Wp = W+2, Hp = H+2;
  int cv = id & 15; int rest = id >> 4;
  int npx = 2*Wp + 2*H;
  int img = rest / npx; int pix = rest - img*npx;
  int hh, wwp;
  if (pix < Wp) { hh = 0; wwp = pix; }
  else if (pix < 2*Wp) { hh = Hp-1; wwp = pix - Wp; }
  else { int r2 = pix - 2*Wp; hh = 1 + (r2 >> 1); wwp = (r2 & 1) ? (Wp-1) : 0; }
  uint4 zv = {0u,0u,0u,0u};
  *(uint4*)(base + (((size_t)img*Hp + hh)*Wp + wwp)*128 + cv*8) = zv;
}

// ---------------- weight prep: fp32 [O][I][kh][kw] -> bf16 [t][O][I] (+convT classes, cb) ----------------
struct WEnt { const float* src; u16* dst; int O, I, T, mode; };
struct WTab { int n; WEnt e[14]; int cum[15]; };
__global__ __launch_bounds__(256) void prep_w(WTab wt) {
  int id = blockIdx.x*256 + threadIdx.x;
  if (id >= wt.cum[wt.n]) return;
  int k = 0;
  while (id >= wt.cum[k+1]) k++;
  int l = id - wt.cum[k];
  WEnt E = wt.e[k];
  if (E.mode == 0) {
    int i = l % E.I; int rest = l / E.I; int o = rest % E.O; int t = rest / E.O;
    E.dst[l] = f2bf(E.src[(o*E.I + i)*E.T + t]);
  } else if (E.mode == 1) {                 // convT dt1: [I][O][4][4] -> [cls][tt][O][I]
    int i = l & 127, o = (l >> 7) & 127, tt = (l >> 14) & 3, cls = l >> 16;
    int th = tt >> 1, tw = tt & 1, po = cls >> 1, pw = cls & 1;
    int kh = po ? (th ? 2 : 0) : (th ? 3 : 1);
    int kw = pw ? (tw ? 2 : 0) : (tw ? 3 : 1);
    E.dst[l] = f2bf(E.src[((i*128 + o)*4 + kh)*4 + kw]);
  } else if (E.mode == 2) {                 // codebook cast
    E.dst[l] = f2bf(E.src[l]);
  } else {                                  // codebook 0.5*||e||^2
    float s = 0.f; const float* r = E.src + l*128;
    for (int c=0;c<128;c++) s += r[c]*r[c];
    ((float*)E.dst)[l] = 0.5f*s;
  }
}

// ---------------- e1: 3->128, k4 s2 p1, fp32 direct, relu, -> bf16 NHWC halo ----------------
__global__ __launch_bounds__(256) void conv_e1(
    const float* __restrict__ x, const float* __restrict__ wr,
    const float* __restrict__ bias, u16* __restrict__ outI)
{
  __shared__ floatx4 wsm[48*32];
  __shared__ float bs[128];
  const int tid = threadIdx.x;
  for (int l = tid; l < 1536; l += 256) {
    int o4 = l & 31, tap = l >> 5;
    int c = tap >> 4, kk = tap & 15;
    floatx4 v;
#pragma unroll
    for (int j=0;j<4;j++) v[j] = wr[((o4*4+j)*3 + c)*16 + kk];
    wsm[tap*32 + o4] = v;
  }
  if (tid < 128) bs[tid] = bias[tid];
  __syncthreads();
  const int pb = blockIdx.x*8 + (tid >> 5);
  const int b = pb >> 14, ho = (pb >> 7) & 127, wo = pb & 127;
  const int o4 = tid & 31;
  floatx4 a = *(floatx4*)&bs[o4*4];
#pragma unroll
  for (int c=0;c<3;c++)
#pragma unroll
    for (int kh=0;kh<4;kh++) {
      int hi = 2*ho + kh - 1;
      const float* xr = x + ((b*3 + c) << 16) + (hi << 8);
      bool hv = (unsigned)hi < 256u;
#pragma unroll
      for (int kw=0;kw<4;kw++) {
        int wi = 2*wo + kw - 1;
        float xv = (hv && (unsigned)wi < 256u) ? xr[wi] : 0.f;
        a += xv * wsm[(c*16 + kh*4 + kw)*32 + o4];
      }
    }
  union { u16 u[4]; uint2 v2; } pk;
#pragma unroll
  for (int j=0;j<4;j++) pk.u[j] = f2bf(fmaxf(a[j], 0.f));
  *(uint2*)&outI[b*IS130 + ho*RS130 + wo*128 + o4*4] = pk.v2;
}

// ---------------- dt2: convT 128->3, k4 s2 p1, direct, -> fp32 NCHW ----------------
__global__ __launch_bounds__(256) void conv_dt2(
    const u16* __restrict__ inI, const float* __restrict__ wr,
    const float* __restrict__ bias, float* __restrict__ xhat)
{
  __shared__ floatx4 wsm[48*32];   // [(k*3+o)][c4]
  const int tid = threadIdx.x;
  for (int l = tid; l < 1536; l += 256) {
    int c4 = l & 31, rest = l >> 5;
    int o = rest % 3, kk = rest / 3;
    floatx4 v;
#pragma unroll
    for (int j=0;j<4;j++) v[j] = wr[((c4*4+j)*3 + o)*16 + kk];
    wsm[(kk*3 + o)*32 + c4] = v;
  }
  __syncthreads();
  const int bh = blockIdx.x;
  const int b = bh >> 8, ho = bh & 255, wo = tid;
  const int ph = ho & 1, pw = wo & 1;
  const int hi0 = ph ? ((ho+1)>>1) : (ho>>1);
  const int kh0 = ph ? 0 : 1;
  const int wi0 = pw ? ((wo+1)>>1) : (wo>>1);
  const int kw0 = pw ? 0 : 1;
  float a0=0.f, a1=0.f, a2=0.f;
#pragma unroll
  for (int th=0; th<2; th++) {
    const int hi = hi0 - th, kh = kh0 + 2*th;
#pragma unroll
    for (int tw=0; tw<2; tw++) {
      const int wi = wi0 - tw, kw = kw0 + 2*tw;
      const u16* ip = inI + b*IS130 + hi*RS130 + wi*128;
      const int kk = kh*4 + kw;
      const floatx4* w0 = &wsm[(kk*3 + 0)*32];
      const floatx4* w1 = &wsm[(kk*3 + 1)*32];
      const floatx4* w2 = &wsm[(kk*3 + 2)*32];
#pragma unroll
      for (int c8 = 0; c8 < 16; c8++) {
        uint4 iv = *(const uint4*)(ip + c8*8);
        float f0 = __uint_as_float(iv.x << 16), f1 = __uint_as_float(iv.x & 0xFFFF0000u);
        float f2 = __uint_as_float(iv.y << 16), f3 = __uint_as_float(iv.y & 0xFFFF0000u);
        float f4 = __uint_as_float(iv.z << 16), f5 = __uint_as_float(iv.z & 0xFFFF0000u);
        float f6 = __uint_as_float(iv.w << 16), f7 = __uint_as_float(iv.w & 0xFFFF0000u);
        floatx4 wa, wb;
        wa = w0[c8*2]; wb = w0[c8*2+1];
        a0 += f0*wa[0]+f1*wa[1]+f2*wa[2]+f3*wa[3]+f4*wb[0]+f5*wb[1]+f6*wb[2]+f7*wb[3];
        wa = w1[c8*2]; wb = w1[c8*2+1];
        a1 += f0*wa[0]+f1*wa[1]+f2*wa[2]+f3*wa[3]+f4*wb[0]+f5*wb[1]+f6*wb[2]+f7*wb[3];
        wa = w2[c8*2]; wb = w2[c8*2+1];
        a2 += f0*wa[0]+f1*wa[1]+f2*wa[2]+f3*wa[3]+f4*wb[0]+f5*wb[1]+f6*wb[2]+f7*wb[3];
      }
    }
  }
  const int ob = ((b*3) << 16) + (ho << 8) + wo;
  xhat[ob]          = a0 + bias[0];
  xhat[ob + 65536]  = a1 + bias[1];
  xhat[ob + 131072] = a2 + bias[2];
}

// =====================================================================================
extern "C" void kernel_launch(void* const* d_in, const int* in_sizes, int n_in,
                              void* d_out, int out_size, void* d_ws, size_t ws_size,
                              hipStream_t stream)
{
  const float* x     = (const float*)d_in[0];
  const float* e1w   = (const float*)d_in[1];
  const float* e1b   = (const float*)d_in[2];
  const float* e2w   = (const float*)d_in[3];
  const float* e2b   = (const float*)d_in[4];
  const float* e3w   = (const float*)d_in[5];
  const float* e3b   = (const float*)d_in[6];
  const float* er1aw = (const float*)d_in[7];
  const float* er1ab = (const float*)d_in[8];
  const float* er1bw = (const float*)d_in[9];
  const float* er1bb = (const float*)d_in[10];
  const float* er2aw = (const float*)d_in[11];
  const float* er2ab = (const float*)d_in[12];
  const float* er2bw = (const float*)d_in[13];
  const float* er2bb = (const float*)d_in[14];
  const float* cb    = (const float*)d_in[15];
  const float* d1w   = (const float*)d_in[16];
  const float* d1b   = (const float*)d_in[17];
  const float* dr1aw = (const float*)d_in[18];
  const float* dr1ab = (const float*)d_in[19];
  const float* dr1bw = (const float*)d_in[20];
  const float* dr1bb = (const float*)d_in[21];
  const float* dr2aw = (const float*)d_in[22];
  const float* dr2ab = (const float*)d_in[23];
  const float* dr2bw = (const float*)d_in[24];
  const float* dr2bb = (const float*)d_in[25];
  const float* dt1w  = (const float*)d_in[26];
  const float* dt1b  = (const float*)d_in[27];
  const float* dt2w  = (const float*)d_in[28];
  const float* dt2b  = (const float*)d_in[29];
  float* out = (float*)d_out;

  char* ws = (char*)d_ws;
  size_t off = 0;
  auto alloc = [&](size_t bytes) -> void* {
    void* r = ws + off; off += (bytes + 255) & ~(size_t)255; return r;
  };

  // total ~143 MB
  u16* BIG = (u16*)alloc((size_t)IS130*16*2);      // e1-out, later dt1-out (130x130 halo)
  u16* S[4];
  for (int i=0;i<4;i++) S[i] = (u16*)alloc((size_t)IS66*16*2);
  unsigned long long* minb = (unsigned long long*)alloc((size_t)65536*8);
  u16* W_e2 = (u16*)alloc(262144*2);
  u16* W9[6]; for (int i=0;i<6;i++) W9[i] = (u16*)alloc(147456*2);
  u16* W1[4]; for (int i=0;i<4;i++) W1[i] = (u16*)alloc(16384*2);
  u16* Wdt1 = (u16*)alloc(262144*2);
  u16* cbBF = (u16*)alloc(65536*2);
  float* cbn = (float*)alloc(512*4);

  u16* BIGi = BIG + RS130 + 128;
  u16* Si[4];
  for (int i=0;i<4;i++) Si[i] = S[i] + RS66 + 128;
  u16* zeBFc = S[1];   // compact [p][c] VQ A-matrix reuses S1 storage (t2 dead by then)

  // 1. zero halos + init minb (ws is re-poisoned before every timed launch)
  zero_halos<<<1812, 256, 0, stream>>>(BIG, S[0], S[1], S[2], S[3], minb);

  // 2. weights -> bf16 [t][O][I] layouts (+codebook)
  WTab wtab; int ne = 0; wtab.cum[0] = 0;
  auto addw = [&](const float* s, u16* d, int O, int I, int T, int m, int items) {
    wtab.e[ne] = {s, d, O, I, T, m};
    wtab.cum[ne+1] = wtab.cum[ne] + items; ne++;
  };
  addw(e2w,   W_e2, 128,128,16,0, 262144);
  addw(e3w,   W9[0],128,128, 9,0, 147456);
  addw(er1aw, W9[1],128,128, 9,0, 147456);
  addw(er2aw, W9[2],128,128, 9,0, 147456);
  addw(d1w,   W9[3],128,128, 9,0, 147456);
  addw(dr1aw, W9[4],128,128, 9,0, 147456);
  addw(dr2aw, W9[5],128,128, 9,0, 147456);
  addw(er1bw, W1[0],128,128, 1,0, 16384);
  addw(er2bw, W1[1],128,128, 1,0, 16384);
  addw(dr1bw, W1[2],128,128, 1,0, 16384);
  addw(dr2bw, W1[3],128,128, 1,0, 16384);
  addw(dt1w,  Wdt1, 0,0,0,1, 262144);
  addw(cb,    cbBF, 0,0,0,2, 65536);
  addw(cb,    (u16*)cbn, 0,0,0,3, 512);
  wtab.n = ne;
  prep_w<<<(wtab.cum[ne] + 255)/256, 256, 0, stream>>>(wtab);

  // 3. e1 (fp32 direct)
  conv_e1<<<32768, 256, 0, stream>>>(x, e1w, e1b, BIGi);

  // taps
  Taps t16; t16.n = 16; t16.dh2 = 0; t16.dw2 = 0;
  for (int t=0;t<16;t++) { t16.dh2 |= (unsigned)(t>>2) << (2*t); t16.dw2 |= (unsigned)(t&3) << (2*t); }
  Taps t9; t9.n = 9; t9.dh2 = 0; t9.dw2 = 0;
  for (int t=0;t<9;t++) { t9.dh2 |= (unsigned)(t/3) << (2*t); t9.dw2 |= (unsigned)(t%3) << (2*t); }
  Taps t1x; t1x.n = 1; t1x.dh2 = 1; t1x.dw2 = 1;
  Taps tc[4];
  for (int cls=0; cls<4; ++cls) {
    int po = cls >> 1, pw = cls & 1;
    tc[cls].n = 4; tc[cls].dh2 = 0; tc[cls].dw2 = 0;
    for (int tt=0; tt<4; ++tt) {
      int th = tt >> 1, tw = tt & 1;
      int dh = po ? (th ? 0 : 1) : (th ? -1 : 0);
      int dw = pw ? (tw ? 0 : 1) : (tw ? -1 : 0);
      tc[cls].dh2 |= (unsigned)(dh+1) << (2*tt);
      tc[cls].dw2 |= (unsigned)(dw+1) << (2*tt);
    }
  }

  auto conv = [&](const u16* in_, int iRS, int iIS, int si,
                  const u16* w_, const float* b_, Taps tp,
                  u16* o_, int oRS, int oIS, int so, int oh, int ow,
                  const u16* r_, u16* o2, int rl, float* zf, u16* zb) {
    conv_mfma<<<512, 256, 0, stream>>>(in_, iRS, iIS, si, w_, b_, tp,
                                       o_, oRS, oIS, so, oh, ow, r_, o2, rl, zf, zb);
  };

  // encoder
  conv(BIGi, RS130, IS130, 2, W_e2, e2b, t16, Si[0], RS66, IS66, 1,0,0, nullptr, nullptr, 1, nullptr, nullptr); // e2 -> S0 (relu)
  conv(Si[0], RS66, IS66, 1, W9[0], e3b, t9, Si[1], RS66, IS66, 1,0,0, nullptr, Si[2], 0, nullptr, nullptr);    // e3 -> t2=S1, relu->S2
  conv(Si[2], RS66, IS66, 1, W9[1], er1ab, t9, Si[0], RS66, IS66, 1,0,0, nullptr, nullptr, 1, nullptr, nullptr);// er1a -> S0 (relu)
  conv(Si[0], RS66, IS66, 1, W1[0], er1bb, t1x, Si[3], RS66, IS66, 1,0,0, Si[1], Si[2], 0, nullptr, nullptr);   // er1b(+t2) -> t4=S3, relu->S2
  conv(Si[2], RS66, IS66, 1, W9[2], er2ab, t9, Si[0], RS66, IS66, 1,0,0, nullptr, nullptr, 1, nullptr, nullptr);// er2a -> S0 (relu)
  conv(Si[0], RS66, IS66, 1, W1[1], er2bb, t1x, nullptr, RS66, IS66, 1,0,0, Si[3], nullptr, 0,
       out + 3145728, zeBFc);                                                                                   // er2b(+t4) -> ze (direct NCHW) + compact bf16

  // VQ
  vq_score<<<dim3(512,4), 256, 0, stream>>>(zeBFc, cbBF, cbn, minb);
  zq_out_k<<<32768, 256, 0, stream>>>(minb, cb, out + 11534336, Si[2]);   // zq fp32 out + bf16 -> S2

  // decoder
  conv(Si[2], RS66, IS66, 1, W9[3], d1b, t9, Si[0], RS66, IS66, 1,0,0, nullptr, Si[1], 0, nullptr, nullptr);    // d1 -> g1=S0, relu->S1
  conv(Si[1], RS66, IS66, 1, W9[4], dr1ab, t9, Si[2], RS66, IS66, 1,0,0, nullptr, nullptr, 1, nullptr, nullptr);// dr1a -> S2 (relu)
  conv(Si[2], RS66, IS66, 1, W1[2], dr1bb, t1x, Si[3], RS66, IS66, 1,0,0, Si[0], Si[1], 0, nullptr, nullptr);   // dr1b(+g1) -> g2=S3, relu->S1
  conv(Si[1], RS66, IS66, 1, W9[5], dr2ab, t9, Si[2], RS66, IS66, 1,0,0, nullptr, nullptr, 1, nullptr, nullptr);// dr2a -> S2 (relu)
  conv(Si[2], RS66, IS66, 1, W1[3], dr2bb, t1x, Si[0], RS66, IS66, 1,0,0, Si[3], nullptr, 0, nullptr, nullptr); // dr2b(+g2) -> g3=S0

  // dt1: convT as 4 parity-class stride-1 convs, relu
  for (int cls=0; cls<4; ++cls) {
    int po = cls >> 1, pw = cls & 1;
    conv(Si[0], RS66, IS66, 1, Wdt1 + cls*65536, dt1b, tc[cls],
         BIGi, RS130, IS130, 2, po, pw, nullptr, nullptr, 1, nullptr, nullptr);
  }

  // dt2 -> x_hat (NCHW fp32)
  conv_dt2<<<4096, 256, 0, stream>>>(BIGi, dt2w, dt2b, out);
}

// Round 3
// 875.214 us; speedup vs baseline: 1.5926x; 1.5926x over previous
//
#include <hip/hip_runtime.h>
#include <stdint.h>

typedef unsigned short u16;
typedef __attribute__((ext_vector_type(8))) short short8;
typedef __attribute__((ext_vector_type(4))) float floatx4;

#define RS66  (66*128)
#define IS66  (66*66*128)
#define RS130 (130*128)
#define IS130 (130*130*128)

__device__ __forceinline__ float bf2f(u16 h) {
  union { unsigned u; float f; } v; v.u = ((unsigned)h) << 16; return v.f;
}
__device__ __forceinline__ u16 f2bf(float f) {
  union { float f; unsigned u; } v; v.f = f;
  unsigned r = v.u + 0x7FFFu + ((v.u >> 16) & 1u);
  return (u16)(r >> 16);
}
__device__ __forceinline__ void gl_lds16(const void* g, void* l) {
  __builtin_amdgcn_global_load_lds(
      (const __attribute__((address_space(1))) void*)(uintptr_t)g,
      (__attribute__((address_space(3))) void*)(uintptr_t)l, 16, 0, 0);
}
__device__ __forceinline__ unsigned fkey(float f) {
  unsigned u = __float_as_uint(f);
  return (u & 0x80000000u) ? ~u : (u | 0x80000000u);
}

struct Taps { int n; unsigned dh2; unsigned dw2; };  // 2-bit packed offsets, stored val = d+1

// ---------------- MFMA implicit-GEMM conv: tile 128 pixels x 128 outch, K=taps*128 ----------------
__global__ __launch_bounds__(256) void conv_mfma(
    const u16* __restrict__ in, int inRS, int inIS, int si,
    const u16* __restrict__ wt, const float* __restrict__ bias, Taps tp,
    u16* __restrict__ out, int outRS, int outIS, int so, int oh0, int ow0,
    const u16* __restrict__ res, u16* __restrict__ out2, int reluMain,
    float* __restrict__ zeOut, u16* __restrict__ zeBFc)
{
  __shared__ u16 lA[4096];
  __shared__ u16 lB[4096];
  const int tid = threadIdx.x;
  const int w = tid >> 6, lane = tid & 63, quad = lane >> 4, l16 = lane & 15;
  const int wm = w >> 1, wn = w & 1;
  const int q = tid & 3, p0 = tid >> 2;
  const int blockM = blockIdx.x << 7;
  const int pg0 = blockM + p0, pg1 = pg0 + 64;
  const int b0 = pg0 >> 12, mo0 = (pg0 >> 6) & 63, no0 = pg0 & 63;
  const int b1 = pg1 >> 12, mo1 = (pg1 >> 6) & 63, no1 = pg1 & 63;
  const u16* gA0 = in + b0*inIS + si*mo0*inRS + si*no0*128 + q*8;
  const u16* gA1 = in + b1*inIS + si*mo1*inRS + si*no1*128 + q*8;
  const u16* gB0 = wt + p0*128 + q*8;
  const u16* gB1 = gB0 + 64*128;
  u16* lsA0 = lA + w*512; u16* lsA1 = lsA0 + 2048;
  u16* lsB0 = lB + w*512; u16* lsB1 = lsB0 + 2048;

  floatx4 zz = {0.f,0.f,0.f,0.f};
  floatx4 acc[4][4];
#pragma unroll
  for (int i=0;i<4;i++)
#pragma unroll
    for (int j=0;j<4;j++) acc[i][j] = zz;

  for (int t = 0; t < tp.n; ++t) {
    const int dh = (int)((tp.dh2 >> (2*t)) & 3u) - 1;
    const int dw = (int)((tp.dw2 >> (2*t)) & 3u) - 1;
    const int aoff = dh*inRS + dw*128;
    const int boff = t << 14;
#pragma unroll
    for (int kc = 0; kc < 4; ++kc) {
      __syncthreads();
      gl_lds16(gA0 + aoff + kc*32, lsA0);
      gl_lds16(gA1 + aoff + kc*32, lsA1);
      gl_lds16(gB0 + boff + kc*32, lsB0);
      gl_lds16(gB1 + boff + kc*32, lsB1);
      __syncthreads();
      short8 af[4], bfr[4];
#pragma unroll
      for (int s=0;s<4;s++) af[s]  = *(const short8*)&lA[(wm*64 + s*16 + l16)*32 + quad*8];
#pragma unroll
      for (int s=0;s<4;s++) bfr[s] = *(const short8*)&lB[(wn*64 + s*16 + l16)*32 + quad*8];
#pragma unroll
      for (int i=0;i<4;i++)
#pragma unroll
        for (int j=0;j<4;j++)
          acc[i][j] = __builtin_amdgcn_mfma_f32_16x16x32_bf16(af[i], bfr[j], acc[i][j], 0, 0, 0);
    }
  }

  float bv[4];
#pragma unroll
  for (int j=0;j<4;j++) bv[j] = bias[wn*64 + j*16 + l16];

#pragma unroll
  for (int i=0;i<4;i++) {
#pragma unroll
    for (int r=0;r<4;r++) {
      const int p = blockM + wm*64 + i*16 + quad*4 + r;
      const int bb = p >> 12, mo = (p >> 6) & 63, no = p & 63;
      const int ob = bb*outIS + (so*mo + oh0)*outRS + (so*no + ow0)*128;
#pragma unroll
      for (int j=0;j<4;j++) {
        const int n = wn*64 + j*16 + l16;
        float v = acc[i][j][r] + bv[j];
        if (res)  v += bf2f(res[ob + n]);
        if (out)  out[ob + n]  = f2bf(reluMain ? fmaxf(v, 0.f) : v);
        if (out2) out2[ob + n] = f2bf(fmaxf(v, 0.f));
        if (zeOut) {
          zeOut[(((size_t)bb) << 19) + ((size_t)n << 12) + (p & 4095)] = v;  // NCHW fp32 direct
          zeBFc[((size_t)p << 7) + n] = f2bf(v);                             // compact for VQ
        }
      }
    }
  }
}

// ---------------- VQ: scores = ze . cb^T, per-pixel argmin via packed atomicMin ----------------
__global__ __launch_bounds__(256) void vq_score(
    const u16* __restrict__ zeBF, const u16* __restrict__ cbBF,
    const float* __restrict__ cbn, unsigned long long* __restrict__ minbuf)
{
  __shared__ u16 lA[4096];
  __shared__ u16 lB[4096];
  const int tid = threadIdx.x;
  const int w = tid >> 6, lane = tid & 63, quad = lane >> 4, l16 = lane & 15;
  const int wm = w >> 1, wn = w & 1;
  const int q = tid & 3, p0 = tid >> 2;
  const int blockM = blockIdx.x << 7;
  const int nb = blockIdx.y;
  const u16* gA0 = zeBF + ((blockM + p0) << 7) + q*8;
  const u16* gA1 = gA0 + (64 << 7);
  const u16* gB0 = cbBF + ((nb*128 + p0) << 7) + q*8;
  const u16* gB1 = gB0 + (64 << 7);
  u16* lsA0 = lA + w*512; u16* lsA1 = lsA0 + 2048;
  u16* lsB0 = lB + w*512; u16* lsB1 = lsB0 + 2048;

  floatx4 zz = {0.f,0.f,0.f,0.f};
  floatx4 acc[4][4];
#pragma unroll
  for (int i=0;i<4;i++)
#pragma unroll
    for (int j=0;j<4;j++) acc[i][j] = zz;

#pragma unroll
  for (int kc = 0; kc < 4; ++kc) {
    __syncthreads();
    gl_lds16(gA0 + kc*32, lsA0);
    gl_lds16(gA1 + kc*32, lsA1);
    gl_lds16(gB0 + kc*32, lsB0);
    gl_lds16(gB1 + kc*32, lsB1);
    __syncthreads();
    short8 af[4], bfr[4];
#pragma unroll
    for (int s=0;s<4;s++) af[s]  = *(const short8*)&lA[(wm*64 + s*16 + l16)*32 + quad*8];
#pragma unroll
    for (int s=0;s<4;s++) bfr[s] = *(const short8*)&lB[(wn*64 + s*16 + l16)*32 + quad*8];
#pragma unroll
    for (int i=0;i<4;i++)
#pragma unroll
      for (int j=0;j<4;j++)
        acc[i][j] = __builtin_amdgcn_mfma_f32_16x16x32_bf16(af[i], bfr[j], acc[i][j], 0, 0, 0);
  }

  float cn[4];
#pragma unroll
  for (int j=0;j<4;j++) cn[j] = cbn[nb*128 + wn*64 + j*16 + l16];

#pragma unroll
  for (int i=0;i<4;i++) {
#pragma unroll
    for (int r=0;r<4;r++) {
      const int p = blockM + wm*64 + i*16 + quad*4 + r;
      unsigned long long best = 0xFFFFFFFFFFFFFFFFull;
#pragma unroll
      for (int j=0;j<4;j++) {
        const int n = nb*128 + wn*64 + j*16 + l16;
        float v = cn[j] - acc[i][j][r];       // 0.5||e||^2 - z.e  (same argmin as L2 dist)
        unsigned long long pk = ((unsigned long long)fkey(v) << 32) | (unsigned)n;
        if (pk < best) best = pk;
      }
#pragma unroll
      for (int d=1; d<16; d<<=1) {
        unsigned long long o = __shfl_xor(best, d, 64);
        if (o < best) best = o;
      }
      if (l16 == 0) atomicMin(minbuf + p, best);
    }
  }
}

// ---------------- zq: gather codebook -> fp32 NCHW out + bf16 padded decoder input ----------------
__global__ __launch_bounds__(256) void zq_out_k(
    const unsigned long long* __restrict__ minb, const float* __restrict__ cb,
    float* __restrict__ outZ, u16* __restrict__ zqI)
{
  int id = blockIdx.x*256 + threadIdx.x;   // 16*4096*128
  int c = id & 127, p = id >> 7;
  int n = (int)(unsigned)(minb[p] & 0xFFFFFFFFull);
  float v = cb[(n << 7) + c];
  int b = p >> 12, hw = p & 4095;
  outZ[(((size_t)b) << 19) + ((size_t)c << 12) + hw] = v;   // NCHW (scattered; L2 merges)
  int h = hw >> 6, w2 = hw & 63;
  zqI[b*IS66 + h*RS66 + w2*128 + c] = f2bf(v);              // coalesced (interior)
}

// ---------------- zero halos + init VQ argmin buffer ----------------
__global__ __launch_bounds__(256) void zero_halos(
    u16* big, u16* s0, u16* s1, u16* s2, u16* s3, unsigned long long* minb)
{
  int id = blockIdx.x*256 + threadIdx.x;
  if (id >= 463872) return;
  if (id >= 398336) { minb[id - 398336] = 0xFFFFFFFFFFFFFFFFull; return; }
  u16* base; int H, W;
  if (id < 132096) { base = big; H = 128; W = 128; }
  else {
    id -= 132096;
    int bi = id / 66560;
    id -= bi*66560;
    base = (bi == 0) ? s0 : (bi == 1) ? s1 : (bi == 2) ? s2 : s3;
    H = 64; W = 64;
  }
  int Wp = W+2, Hp = H+2;
  int cv = id & 15; int rest = id >> 4;
  int npx = 2*Wp + 2*H;
  int img = rest / npx; int pix = rest - img*npx;
  int hh, wwp;
  if (pix < Wp) { hh = 0; wwp = pix; }
  else if (pix < 2*Wp) { hh = Hp-1; wwp = pix - Wp; }
  else { int r2 = pix - 2*Wp; hh = 1 + (r2 >> 1); wwp = (r2 & 1) ? (Wp-1) : 0; }
  uint4 zv = {0u,0u,0u,0u};
  *(uint4*)(base + (((size_t)img*Hp + hh)*Wp + wwp)*128 + cv*8) = zv;
}

// ---------------- weight prep ----------------
struct WEnt { const float* src; u16* dst; int O, I, T, mode; };
struct WTab { int n; WEnt e[16]; int cum[17]; };
__global__ __launch_bounds__(256) void prep_w(WTab wt) {
  int id = blockIdx.x*256 + threadIdx.x;
  if (id >= wt.cum[wt.n]) return;
  int k = 0;
  while (id >= wt.cum[k+1]) k++;
  int l = id - wt.cum[k];
  WEnt E = wt.e[k];
  if (E.mode == 0) {
    int i = l % E.I; int rest = l / E.I; int o = rest % E.O; int t = rest / E.O;
    E.dst[l] = f2bf(E.src[(o*E.I + i)*E.T + t]);
  } else if (E.mode == 1) {                 // convT dt1: [I][O][4][4] -> [cls][tt][O][I]
    int i = l & 127, o = (l >> 7) & 127, tt = (l >> 14) & 3, cls = l >> 16;
    int th = tt >> 1, tw = tt & 1, po = cls >> 1, pw = cls & 1;
    int kh = po ? (th ? 2 : 0) : (th ? 3 : 1);
    int kw = pw ? (tw ? 2 : 0) : (tw ? 3 : 1);
    E.dst[l] = f2bf(E.src[((i*128 + o)*4 + kh)*4 + kw]);
  } else if (E.mode == 2) {                 // codebook cast
    E.dst[l] = f2bf(E.src[l]);
  } else if (E.mode == 3) {                 // codebook 0.5*||e||^2
    float s = 0.f; const float* r = E.src + l*128;
    for (int c=0;c<128;c++) s += r[c]*r[c];
    ((float*)E.dst)[l] = 0.5f*s;
  } else {                                  // mode 4: e1 weights fp32 [o][48] -> [tap][o]
    int o = l & 127, tap = l >> 7;
    ((float*)E.dst)[l] = E.src[o*48 + tap];
  }
}

// ---------------- e1: 3->128, k4 s2 p1, row-tiled direct fp32, relu -> bf16 NHWC halo ----------------
// one block per (b, ho): 128 out pixels x 128 ch. Input row tile + weights staged in LDS once.
__global__ __launch_bounds__(256) void conv_e1(
    const float* __restrict__ x, const float* __restrict__ wT,   // wT: [tap48][o128] fp32
    const float* __restrict__ bias, u16* __restrict__ outI)
{
  __shared__ float inS[12*260];   // [c*4+kh][col 260], col j = global col j-1
  __shared__ float wS[48*128];    // [tap][o]
  __shared__ float bS[128];
  const int tid = threadIdx.x;
  const int b = blockIdx.x >> 7, ho = blockIdx.x & 127;

  // stage weights (coalesced float4)
  for (int l = tid; l < 1536; l += 256)
    ((float4*)wS)[l] = ((const float4*)wT)[l];
  if (tid < 128) bS[tid] = bias[tid];
  // stage input rows (3ch x 4 rows x 260 cols, OOB -> 0)
  for (int l = tid; l < 3120; l += 256) {
    int col = l % 260; int rest = l / 260;        // rest = c*4+kh
    int kh = rest & 3, c = rest >> 2;
    int hi = 2*ho + kh - 1, wi = col - 1;
    float v = 0.f;
    if ((unsigned)hi < 256u && (unsigned)wi < 256u)
      v = x[((b*3 + c) << 16) + (hi << 8) + wi];
    inS[rest*260 + col] = v;
  }
  __syncthreads();

  const int g = tid & 7;          // channel group: ch0 = g*16
  const int pxg = tid >> 3;       // pixel group: wo0 = pxg*4
  floatx4 acc[4][4];
  {
    const floatx4* bp = (const floatx4*)&bS[g*16];
    floatx4 b0 = bp[0], b1 = bp[1], b2 = bp[2], b3 = bp[3];
#pragma unroll
    for (int px=0;px<4;px++) { acc[px][0]=b0; acc[px][1]=b1; acc[px][2]=b2; acc[px][3]=b3; }
  }
#pragma unroll
  for (int c=0;c<3;c++)
#pragma unroll
    for (int kh=0;kh<4;kh++) {
      const float* row = &inS[(c*4+kh)*260];
#pragma unroll
      for (int kw=0;kw<4;kw++) {
        const int tap = c*16 + kh*4 + kw;
        const floatx4* wp = (const floatx4*)&wS[tap*128 + g*16];
        floatx4 w0 = wp[0], w1 = wp[1], w2 = wp[2], w3 = wp[3];
#pragma unroll
        for (int px=0;px<4;px++) {
          float xv = row[((pxg*4 + px) << 1) + kw];
          acc[px][0] += xv*w0; acc[px][1] += xv*w1;
          acc[px][2] += xv*w2; acc[px][3] += xv*w3;
        }
      }
    }

  u16* ob = outI + b*IS130 + ho*RS130;
#pragma unroll
  for (int px=0;px<4;px++) {
    const int wo = pxg*4 + px;
    u16* p = ob + wo*128 + g*16;
#pragma unroll
    for (int k=0;k<4;k++) {
      union { u16 u[4]; uint2 v2; } pk;
#pragma unroll
      for (int j=0;j<4;j++) pk.u[j] = f2bf(fmaxf(acc[px][k][j], 0.f));
      *(uint2*)(p + k*4) = pk.v2;
    }
  }
}

// ---------------- dt2: convT 128->3, k4 s2 p1, direct, -> fp32 NCHW ----------------
__global__ __launch_bounds__(256) void conv_dt2(
    const u16* __restrict__ inI, const float* __restrict__ wr,
    const float* __restrict__ bias, float* __restrict__ xhat)
{
  __shared__ floatx4 wsm[48*32];   // [(k*3+o)][c4]
  const int tid = threadIdx.x;
  for (int l = tid; l < 1536; l += 256) {
    int c4 = l & 31, rest = l >> 5;
    int o = rest % 3, kk = rest / 3;
    floatx4 v;
#pragma unroll
    for (int j=0;j<4;j++) v[j] = wr[((c4*4+j)*3 + o)*16 + kk];
    wsm[(kk*3 + o)*32 + c4] = v;
  }
  __syncthreads();
  const int bh = blockIdx.x;
  const int b = bh >> 8, ho = bh & 255, wo = tid;
  const int ph = ho & 1, pw = wo & 1;
  const int hi0 = ph ? ((ho+1)>>1) : (ho>>1);
  const int kh0 = ph ? 0 : 1;
  const int wi0 = pw ? ((wo+1)>>1) : (wo>>1);
  const int kw0 = pw ? 0 : 1;
  float a0=0.f, a1=0.f, a2=0.f;
#pragma unroll
  for (int th=0; th<2; th++) {
    const int hi = hi0 - th, kh = kh0 + 2*th;
#pragma unroll
    for (int tw=0; tw<2; tw++) {
      const int wi = wi0 - tw, kw = kw0 + 2*tw;
      const u16* ip = inI + b*IS130 + hi*RS130 + wi*128;
      const int kk = kh*4 + kw;
      const floatx4* w0 = &wsm[(kk*3 + 0)*32];
      const floatx4* w1 = &wsm[(kk*3 + 1)*32];
      const floatx4* w2 = &wsm[(kk*3 + 2)*32];
#pragma unroll
      for (int c8 = 0; c8 < 16; c8++) {
        uint4 iv = *(const uint4*)(ip + c8*8);
        float f0 = __uint_as_float(iv.x << 16), f1 = __uint_as_float(iv.x & 0xFFFF0000u);
        float f2 = __uint_as_float(iv.y << 16), f3 = __uint_as_float(iv.y & 0xFFFF0000u);
        float f4 = __uint_as_float(iv.z << 16), f5 = __uint_as_float(iv.z & 0xFFFF0000u);
        float f6 = __uint_as_float(iv.w << 16), f7 = __uint_as_float(iv.w & 0xFFFF0000u);
        floatx4 wa, wb;
        wa = w0[c8*2]; wb = w0[c8*2+1];
        a0 += f0*wa[0]+f1*wa[1]+f2*wa[2]+f3*wa[3]+f4*wb[0]+f5*wb[1]+f6*wb[2]+f7*wb[3];
        wa = w1[c8*2]; wb = w1[c8*2+1];
        a1 += f0*wa[0]+f1*wa[1]+f2*wa[2]+f3*wa[3]+f4*wb[0]+f5*wb[1]+f6*wb[2]+f7*wb[3];
        wa = w2[c8*2]; wb = w2[c8*2+1];
        a2 += f0*wa[0]+f1*wa[1]+f2*wa[2]+f3*wa[3]+f4*wb[0]+f5*wb[1]+f6*wb[2]+f7*wb[3];
      }
    }
  }
  const int ob = ((b*3) << 16) + (ho << 8) + wo;
  xhat[ob]          = a0 + bias[0];
  xhat[ob + 65536]  = a1 + bias[1];
  xhat[ob + 131072] = a2 + bias[2];
}

// =====================================================================================
extern "C" void kernel_launch(void* const* d_in, const int* in_sizes, int n_in,
                              void* d_out, int out_size, void* d_ws, size_t ws_size,
                              hipStream_t stream)
{
  const float* x     = (const float*)d_in[0];
  const float* e1w   = (const float*)d_in[1];
  const float* e1b   = (const float*)d_in[2];
  const float* e2w   = (const float*)d_in[3];
  const float* e2b   = (const float*)d_in[4];
  const float* e3w   = (const float*)d_in[5];
  const float* e3b   = (const float*)d_in[6];
  const float* er1aw = (const float*)d_in[7];
  const float* er1ab = (const float*)d_in[8];
  const float* er1bw = (const float*)d_in[9];
  const float* er1bb = (const float*)d_in[10];
  const float* er2aw = (const float*)d_in[11];
  const float* er2ab = (const float*)d_in[12];
  const float* er2bw = (const float*)d_in[13];
  const float* er2bb = (const float*)d_in[14];
  const float* cb    = (const float*)d_in[15];
  const float* d1w   = (const float*)d_in[16];
  const float* d1b   = (const float*)d_in[17];
  const float* dr1aw = (const float*)d_in[18];
  const float* dr1ab = (const float*)d_in[19];
  const float* dr1bw = (const float*)d_in[20];
  const float* dr1bb = (const float*)d_in[21];
  const float* dr2aw = (const float*)d_in[22];
  const float* dr2ab = (const float*)d_in[23];
  const float* dr2bw = (const float*)d_in[24];
  const float* dr2bb = (const float*)d_in[25];
  const float* dt1w  = (const float*)d_in[26];
  const float* dt1b  = (const float*)d_in[27];
  const float* dt2w  = (const float*)d_in[28];
  const float* dt2b  = (const float*)d_in[29];
  float* out = (float*)d_out;

  char* ws = (char*)d_ws;
  size_t off = 0;
  auto alloc = [&](size_t bytes) -> void* {
    void* r = ws + off; off += (bytes + 255) & ~(size_t)255; return r;
  };

  u16* BIG = (u16*)alloc((size_t)IS130*16*2);      // e1-out, later dt1-out (130x130 halo)
  u16* S[4];
  for (int i=0;i<4;i++) S[i] = (u16*)alloc((size_t)IS66*16*2);
  unsigned long long* minb = (unsigned long long*)alloc((size_t)65536*8);
  u16* W_e2 = (u16*)alloc(262144*2);
  u16* W9[6]; for (int i=0;i<6;i++) W9[i] = (u16*)alloc(147456*2);
  u16* W1[4]; for (int i=0;i<4;i++) W1[i] = (u16*)alloc(16384*2);
  u16* Wdt1 = (u16*)alloc(262144*2);
  u16* cbBF = (u16*)alloc(65536*2);
  float* cbn = (float*)alloc(512*4);
  float* wsE1 = (float*)alloc(6144*4);

  u16* BIGi = BIG + RS130 + 128;
  u16* Si[4];
  for (int i=0;i<4;i++) Si[i] = S[i] + RS66 + 128;
  u16* zeBFc = S[1];   // compact [p][c] VQ A-matrix reuses S1 storage (t2 dead by then)

  // 1. zero halos + init minb (ws is re-poisoned before every timed launch)
  zero_halos<<<1812, 256, 0, stream>>>(BIG, S[0], S[1], S[2], S[3], minb);

  // 2. weights
  WTab wtab; int ne = 0; wtab.cum[0] = 0;
  auto addw = [&](const float* s, u16* d, int O, int I, int T, int m, int items) {
    wtab.e[ne] = {s, d, O, I, T, m};
    wtab.cum[ne+1] = wtab.cum[ne] + items; ne++;
  };
  addw(e2w,   W_e2, 128,128,16,0, 262144);
  addw(e3w,   W9[0],128,128, 9,0, 147456);
  addw(er1aw, W9[1],128,128, 9,0, 147456);
  addw(er2aw, W9[2],128,128, 9,0, 147456);
  addw(d1w,   W9[3],128,128, 9,0, 147456);
  addw(dr1aw, W9[4],128,128, 9,0, 147456);
  addw(dr2aw, W9[5],128,128, 9,0, 147456);
  addw(er1bw, W1[0],128,128, 1,0, 16384);
  addw(er2bw, W1[1],128,128, 1,0, 16384);
  addw(dr1bw, W1[2],128,128, 1,0, 16384);
  addw(dr2bw, W1[3],128,128, 1,0, 16384);
  addw(dt1w,  Wdt1, 0,0,0,1, 262144);
  addw(cb,    cbBF, 0,0,0,2, 65536);
  addw(cb,    (u16*)cbn, 0,0,0,3, 512);
  addw(e1w,   (u16*)wsE1, 0,0,0,4, 6144);
  wtab.n = ne;
  prep_w<<<(wtab.cum[ne] + 255)/256, 256, 0, stream>>>(wtab);

  // 3. e1 (row-tiled direct fp32)
  conv_e1<<<2048, 256, 0, stream>>>(x, wsE1, e1b, BIGi);

  // taps
  Taps t16; t16.n = 16; t16.dh2 = 0; t16.dw2 = 0;
  for (int t=0;t<16;t++) { t16.dh2 |= (unsigned)(t>>2) << (2*t); t16.dw2 |= (unsigned)(t&3) << (2*t); }
  Taps t9; t9.n = 9; t9.dh2 = 0; t9.dw2 = 0;
  for (int t=0;t<9;t++) { t9.dh2 |= (unsigned)(t/3) << (2*t); t9.dw2 |= (unsigned)(t%3) << (2*t); }
  Taps t1x; t1x.n = 1; t1x.dh2 = 1; t1x.dw2 = 1;
  Taps tc[4];
  for (int cls=0; cls<4; ++cls) {
    int po = cls >> 1, pw = cls & 1;
    tc[cls].n = 4; tc[cls].dh2 = 0; tc[cls].dw2 = 0;
    for (int tt=0; tt<4; ++tt) {
      int th = tt >> 1, tw = tt & 1;
      int dh = po ? (th ? 0 : 1) : (th ? -1 : 0);
      int dw = pw ? (tw ? 0 : 1) : (tw ? -1 : 0);
      tc[cls].dh2 |= (unsigned)(dh+1) << (2*tt);
      tc[cls].dw2 |= (unsigned)(dw+1) << (2*tt);
    }
  }

  auto conv = [&](const u16* in_, int iRS, int iIS, int si,
                  const u16* w_, const float* b_, Taps tp,
                  u16* o_, int oRS, int oIS, int so, int oh, int ow,
                  const u16* r_, u16* o2, int rl, float* zf, u16* zb) {
    conv_mfma<<<512, 256, 0, stream>>>(in_, iRS, iIS, si, w_, b_, tp,
                                       o_, oRS, oIS, so, oh, ow, r_, o2, rl, zf, zb);
  };

  // encoder
  conv(BIGi, RS130, IS130, 2, W_e2, e2b, t16, Si[0], RS66, IS66, 1,0,0, nullptr, nullptr, 1, nullptr, nullptr); // e2 -> S0 (relu)
  conv(Si[0], RS66, IS66, 1, W9[0], e3b, t9, Si[1], RS66, IS66, 1,0,0, nullptr, Si[2], 0, nullptr, nullptr);    // e3 -> t2=S1, relu->S2
  conv(Si[2], RS66, IS66, 1, W9[1], er1ab, t9, Si[0], RS66, IS66, 1,0,0, nullptr, nullptr, 1, nullptr, nullptr);// er1a -> S0 (relu)
  conv(Si[0], RS66, IS66, 1, W1[0], er1bb, t1x, Si[3], RS66, IS66, 1,0,0, Si[1], Si[2], 0, nullptr, nullptr);   // er1b(+t2) -> t4=S3, relu->S2
  conv(Si[2], RS66, IS66, 1, W9[2], er2ab, t9, Si[0], RS66, IS66, 1,0,0, nullptr, nullptr, 1, nullptr, nullptr);// er2a -> S0 (relu)
  conv(Si[0], RS66, IS66, 1, W1[1], er2bb, t1x, nullptr, RS66, IS66, 1,0,0, Si[3], nullptr, 0,
       out + 3145728, zeBFc);                                                                                   // er2b(+t4) -> ze (direct NCHW) + compact bf16

  // VQ
  vq_score<<<dim3(512,4), 256, 0, stream>>>(zeBFc, cbBF, cbn, minb);
  zq_out_k<<<32768, 256, 0, stream>>>(minb, cb, out + 11534336, Si[2]);   // zq fp32 out + bf16 -> S2

  // decoder
  conv(Si[2], RS66, IS66, 1, W9[3], d1b, t9, Si[0], RS66, IS66, 1,0,0, nullptr, Si[1], 0, nullptr, nullptr);    // d1 -> g1=S0, relu->S1
  conv(Si[1], RS66, IS66, 1, W9[4], dr1ab, t9, Si[2], RS66, IS66, 1,0,0, nullptr, nullptr, 1, nullptr, nullptr);// dr1a -> S2 (relu)
  conv(Si[2], RS66, IS66, 1, W1[2], dr1bb, t1x, Si[3], RS66, IS66, 1,0,0, Si[0], Si[1], 0, nullptr, nullptr);   // dr1b(+g1) -> g2=S3, relu->S1
  conv(Si[1], RS66, IS66, 1, W9[5], dr2ab, t9, Si[2], RS66, IS66, 1,0,0, nullptr, nullptr, 1, nullptr, nullptr);// dr2a -> S2 (relu)
  conv(Si[2], RS66, IS66, 1, W1[3], dr2bb, t1x, Si[0], RS66, IS66, 1,0,0, Si[3], nullptr, 0, nullptr, nullptr); // dr2b(+g2) -> g3=S0

  // dt1: convT as 4 parity-class stride-1 convs, relu
  for (int cls=0; cls<4; ++cls) {
    int po = cls >> 1, pw = cls & 1;
    conv(Si[0], RS66, IS66, 1, Wdt1 + cls*65536, dt1b, tc[cls],
         BIGi, RS130, IS130, 2, po, pw, nullptr, nullptr, 1, nullptr, nullptr);
  }

  // dt2 -> x_hat (NCHW fp32)
  conv_dt2<<<4096, 256, 0, stream>>>(BIGi, dt2w, dt2b, out);
}

// Round 4
// 796.005 us; speedup vs baseline: 1.7511x; 1.0995x over previous
//
#include <hip/hip_runtime.h>
#include <stdint.h>

typedef unsigned short u16;
typedef __attribute__((ext_vector_type(8))) short short8;
typedef __attribute__((ext_vector_type(4))) float floatx4;

#define RS66  (66*128)
#define IS66  (66*66*128)
#define RS130 (130*128)
#define IS130 (130*130*128)

__device__ __forceinline__ float bf2f(u16 h) {
  union { unsigned u; float f; } v; v.u = ((unsigned)h) << 16; return v.f;
}
__device__ __forceinline__ u16 f2bf(float f) {
  union { float f; unsigned u; } v; v.f = f;
  unsigned r = v.u + 0x7FFFu + ((v.u >> 16) & 1u);
  return (u16)(r >> 16);
}
__device__ __forceinline__ void gl_lds16(const void* g, void* l) {
  __builtin_amdgcn_global_load_lds(
      (const __attribute__((address_space(1))) void*)(uintptr_t)g,
      (__attribute__((address_space(3))) void*)(uintptr_t)l, 16, 0, 0);
}
__device__ __forceinline__ unsigned fkey(float f) {
  unsigned u = __float_as_uint(f);
  return (u & 0x80000000u) ? ~u : (u | 0x80000000u);
}

struct Taps { int n; unsigned dh2; unsigned dw2; };  // 2-bit packed offsets, stored val = d+1

// ---------------- MFMA implicit-GEMM conv: tile 128 pixels x 128 outch, K=taps*128 ----------------
__global__ __launch_bounds__(256) void conv_mfma(
    const u16* __restrict__ in, int inRS, int inIS, int si,
    const u16* __restrict__ wt, const float* __restrict__ bias, Taps tp,
    u16* __restrict__ out, int outRS, int outIS, int so, int oh0, int ow0,
    const u16* __restrict__ res, u16* __restrict__ out2, int reluMain,
    float* __restrict__ zeOut, u16* __restrict__ zeBFc)
{
  __shared__ u16 lA[4096];
  __shared__ u16 lB[4096];
  const int tid = threadIdx.x;
  const int w = tid >> 6, lane = tid & 63, quad = lane >> 4, l16 = lane & 15;
  const int wm = w >> 1, wn = w & 1;
  const int q = tid & 3, p0 = tid >> 2;
  const int blockM = blockIdx.x << 7;
  const int pg0 = blockM + p0, pg1 = pg0 + 64;
  const int b0 = pg0 >> 12, mo0 = (pg0 >> 6) & 63, no0 = pg0 & 63;
  const int b1 = pg1 >> 12, mo1 = (pg1 >> 6) & 63, no1 = pg1 & 63;
  const u16* gA0 = in + b0*inIS + si*mo0*inRS + si*no0*128 + q*8;
  const u16* gA1 = in + b1*inIS + si*mo1*inRS + si*no1*128 + q*8;
  const u16* gB0 = wt + p0*128 + q*8;
  const u16* gB1 = gB0 + 64*128;
  u16* lsA0 = lA + w*512; u16* lsA1 = lsA0 + 2048;
  u16* lsB0 = lB + w*512; u16* lsB1 = lsB0 + 2048;

  floatx4 zz = {0.f,0.f,0.f,0.f};
  floatx4 acc[4][4];
#pragma unroll
  for (int i=0;i<4;i++)
#pragma unroll
    for (int j=0;j<4;j++) acc[i][j] = zz;

  for (int t = 0; t < tp.n; ++t) {
    const int dh = (int)((tp.dh2 >> (2*t)) & 3u) - 1;
    const int dw = (int)((tp.dw2 >> (2*t)) & 3u) - 1;
    const int aoff = dh*inRS + dw*128;
    const int boff = t << 14;
#pragma unroll
    for (int kc = 0; kc < 4; ++kc) {
      __syncthreads();
      gl_lds16(gA0 + aoff + kc*32, lsA0);
      gl_lds16(gA1 + aoff + kc*32, lsA1);
      gl_lds16(gB0 + boff + kc*32, lsB0);
      gl_lds16(gB1 + boff + kc*32, lsB1);
      __syncthreads();
      short8 af[4], bfr[4];
#pragma unroll
      for (int s=0;s<4;s++) af[s]  = *(const short8*)&lA[(wm*64 + s*16 + l16)*32 + quad*8];
#pragma unroll
      for (int s=0;s<4;s++) bfr[s] = *(const short8*)&lB[(wn*64 + s*16 + l16)*32 + quad*8];
#pragma unroll
      for (int i=0;i<4;i++)
#pragma unroll
        for (int j=0;j<4;j++)
          acc[i][j] = __builtin_amdgcn_mfma_f32_16x16x32_bf16(af[i], bfr[j], acc[i][j], 0, 0, 0);
    }
  }

  float bv[4];
#pragma unroll
  for (int j=0;j<4;j++) bv[j] = bias[wn*64 + j*16 + l16];

#pragma unroll
  for (int i=0;i<4;i++) {
#pragma unroll
    for (int r=0;r<4;r++) {
      const int p = blockM + wm*64 + i*16 + quad*4 + r;
      const int bb = p >> 12, mo = (p >> 6) & 63, no = p & 63;
      const int ob = bb*outIS + (so*mo + oh0)*outRS + (so*no + ow0)*128;
#pragma unroll
      for (int j=0;j<4;j++) {
        const int n = wn*64 + j*16 + l16;
        float v = acc[i][j][r] + bv[j];
        if (res)  v += bf2f(res[ob + n]);
        if (out)  out[ob + n]  = f2bf(reluMain ? fmaxf(v, 0.f) : v);
        if (out2) out2[ob + n] = f2bf(fmaxf(v, 0.f));
        if (zeOut) {
          zeOut[(((size_t)bb) << 19) + ((size_t)n << 12) + (p & 4095)] = v;  // NCHW fp32 direct
          zeBFc[((size_t)p << 7) + n] = f2bf(v);                             // compact for VQ
        }
      }
    }
  }
}

// ---------------- VQ: scores = ze . cb^T, per-pixel argmin via packed atomicMin ----------------
__global__ __launch_bounds__(256) void vq_score(
    const u16* __restrict__ zeBF, const u16* __restrict__ cbBF,
    const float* __restrict__ cbn, unsigned long long* __restrict__ minbuf)
{
  __shared__ u16 lA[4096];
  __shared__ u16 lB[4096];
  const int tid = threadIdx.x;
  const int w = tid >> 6, lane = tid & 63, quad = lane >> 4, l16 = lane & 15;
  const int wm = w >> 1, wn = w & 1;
  const int q = tid & 3, p0 = tid >> 2;
  const int blockM = blockIdx.x << 7;
  const int nb = blockIdx.y;
  const u16* gA0 = zeBF + ((blockM + p0) << 7) + q*8;
  const u16* gA1 = gA0 + (64 << 7);
  const u16* gB0 = cbBF + ((nb*128 + p0) << 7) + q*8;
  const u16* gB1 = gB0 + (64 << 7);
  u16* lsA0 = lA + w*512; u16* lsA1 = lsA0 + 2048;
  u16* lsB0 = lB + w*512; u16* lsB1 = lsB0 + 2048;

  floatx4 zz = {0.f,0.f,0.f,0.f};
  floatx4 acc[4][4];
#pragma unroll
  for (int i=0;i<4;i++)
#pragma unroll
    for (int j=0;j<4;j++) acc[i][j] = zz;

#pragma unroll
  for (int kc = 0; kc < 4; ++kc) {
    __syncthreads();
    gl_lds16(gA0 + kc*32, lsA0);
    gl_lds16(gA1 + kc*32, lsA1);
    gl_lds16(gB0 + kc*32, lsB0);
    gl_lds16(gB1 + kc*32, lsB1);
    __syncthreads();
    short8 af[4], bfr[4];
#pragma unroll
    for (int s=0;s<4;s++) af[s]  = *(const short8*)&lA[(wm*64 + s*16 + l16)*32 + quad*8];
#pragma unroll
    for (int s=0;s<4;s++) bfr[s] = *(const short8*)&lB[(wn*64 + s*16 + l16)*32 + quad*8];
#pragma unroll
    for (int i=0;i<4;i++)
#pragma unroll
      for (int j=0;j<4;j++)
        acc[i][j] = __builtin_amdgcn_mfma_f32_16x16x32_bf16(af[i], bfr[j], acc[i][j], 0, 0, 0);
  }

  float cn[4];
#pragma unroll
  for (int j=0;j<4;j++) cn[j] = cbn[nb*128 + wn*64 + j*16 + l16];

#pragma unroll
  for (int i=0;i<4;i++) {
#pragma unroll
    for (int r=0;r<4;r++) {
      const int p = blockM + wm*64 + i*16 + quad*4 + r;
      unsigned long long best = 0xFFFFFFFFFFFFFFFFull;
#pragma unroll
      for (int j=0;j<4;j++) {
        const int n = nb*128 + wn*64 + j*16 + l16;
        float v = cn[j] - acc[i][j][r];       // 0.5||e||^2 - z.e  (same argmin as L2 dist)
        unsigned long long pk = ((unsigned long long)fkey(v) << 32) | (unsigned)n;
        if (pk < best) best = pk;
      }
#pragma unroll
      for (int d=1; d<16; d<<=1) {
        unsigned long long o = __shfl_xor(best, d, 64);
        if (o < best) best = o;
      }
      if (l16 == 0) atomicMin(minbuf + p, best);
    }
  }
}

// ---------------- zq: gather codebook -> fp32 NCHW out + bf16 padded decoder input ----------------
__global__ __launch_bounds__(256) void zq_out_k(
    const unsigned long long* __restrict__ minb, const float* __restrict__ cb,
    float* __restrict__ outZ, u16* __restrict__ zqI)
{
  int id = blockIdx.x*256 + threadIdx.x;   // 16*4096*128
  int c = id & 127, p = id >> 7;
  int n = (int)(unsigned)(minb[p] & 0xFFFFFFFFull);
  float v = cb[(n << 7) + c];
  int b = p >> 12, hw = p & 4095;
  outZ[(((size_t)b) << 19) + ((size_t)c << 12) + hw] = v;   // NCHW (scattered; L2 merges)
  int h = hw >> 6, w2 = hw & 63;
  zqI[b*IS66 + h*RS66 + w2*128 + c] = f2bf(v);              // coalesced (interior)
}

// ---------------- zero halos + init VQ argmin buffer ----------------
__global__ __launch_bounds__(256) void zero_halos(
    u16* big, u16* s0, u16* s1, u16* s2, u16* s3, unsigned long long* minb)
{
  int id = blockIdx.x*256 + threadIdx.x;
  if (id >= 463872) return;
  if (id >= 398336) { minb[id - 398336] = 0xFFFFFFFFFFFFFFFFull; return; }
  u16* base; int H, W;
  if (id < 132096) { base = big; H = 128; W = 128; }
  else {
    id -= 132096;
    int bi = id / 66560;
    id -= bi*66560;
    base = (bi == 0) ? s0 : (bi == 1) ? s1 : (bi == 2) ? s2 : s3;
    H = 64; W = 64;
  }
  int Wp = W+2, Hp = H+2;
  int cv = id & 15; int rest = id >> 4;
  int npx = 2*Wp + 2*H;
  int img = rest / npx; int pix = rest - img*npx;
  int hh, wwp;
  if (pix < Wp) { hh = 0; wwp = pix; }
  else if (pix < 2*Wp) { hh = Hp-1; wwp = pix - Wp; }
  else { int r2 = pix - 2*Wp; hh = 1 + (r2 >> 1); wwp = (r2 & 1) ? (Wp-1) : 0; }
  uint4 zv = {0u,0u,0u,0u};
  *(uint4*)(base + (((size_t)img*Hp + hh)*Wp + wwp)*128 + cv*8) = zv;
}

// ---------------- weight prep ----------------
struct WEnt { const float* src; u16* dst; int O, I, T, mode; };
struct WTab { int n; WEnt e[16]; int cum[17]; };
__global__ __launch_bounds__(256) void prep_w(WTab wt) {
  int id = blockIdx.x*256 + threadIdx.x;
  if (id >= wt.cum[wt.n]) return;
  int k = 0;
  while (id >= wt.cum[k+1]) k++;
  int l = id - wt.cum[k];
  WEnt E = wt.e[k];
  if (E.mode == 0) {
    int i = l % E.I; int rest = l / E.I; int o = rest % E.O; int t = rest / E.O;
    E.dst[l] = f2bf(E.src[(o*E.I + i)*E.T + t]);
  } else if (E.mode == 1) {                 // convT dt1: [I][O][4][4] -> [cls][tt][O][I]
    int i = l & 127, o = (l >> 7) & 127, tt = (l >> 14) & 3, cls = l >> 16;
    int th = tt >> 1, tw = tt & 1, po = cls >> 1, pw = cls & 1;
    int kh = po ? (th ? 2 : 0) : (th ? 3 : 1);
    int kw = pw ? (tw ? 2 : 0) : (tw ? 3 : 1);
    E.dst[l] = f2bf(E.src[((i*128 + o)*4 + kh)*4 + kw]);
  } else if (E.mode == 2) {                 // codebook cast
    E.dst[l] = f2bf(E.src[l]);
  } else if (E.mode == 3) {                 // codebook 0.5*||e||^2
    float s = 0.f; const float* r = E.src + l*128;
    for (int c=0;c<128;c++) s += r[c]*r[c];
    ((float*)E.dst)[l] = 0.5f*s;
  } else if (E.mode == 4) {                 // e1 weights fp32 [o][48] -> [tap][o]
    int o = l & 127, tap = l >> 7;
    ((float*)E.dst)[l] = E.src[o*48 + tap];
  } else {                                  // mode 5: dt2 [c128][o3][4][4] -> bf16 [n48][c128]
    int c = l & 127, n = l >> 7;            // n = o*16 + kh*4+kw
    int o = n >> 4, kk = n & 15;
    E.dst[l] = f2bf(E.src[c*48 + o*16 + kk]);
  }
}

// ---------------- e1: 3->128, k4 s2 p1, row-tiled direct fp32, relu -> bf16 NHWC halo ----------------
__global__ __launch_bounds__(256) void conv_e1(
    const float* __restrict__ x, const float* __restrict__ wT,   // wT: [tap48][o128] fp32
    const float* __restrict__ bias, u16* __restrict__ outI)
{
  __shared__ float inS[12*260];   // [c*4+kh][col 260], col j = global col j-1
  __shared__ float wS[48*128];    // [tap][o]
  __shared__ float bS[128];
  const int tid = threadIdx.x;
  const int b = blockIdx.x >> 7, ho = blockIdx.x & 127;

  for (int l = tid; l < 1536; l += 256)
    ((float4*)wS)[l] = ((const float4*)wT)[l];
  if (tid < 128) bS[tid] = bias[tid];
  for (int l = tid; l < 3120; l += 256) {
    int col = l % 260; int rest = l / 260;        // rest = c*4+kh
    int kh = rest & 3, c = rest >> 2;
    int hi = 2*ho + kh - 1, wi = col - 1;
    float v = 0.f;
    if ((unsigned)hi < 256u && (unsigned)wi < 256u)
      v = x[((b*3 + c) << 16) + (hi << 8) + wi];
    inS[rest*260 + col] = v;
  }
  __syncthreads();

  const int g = tid & 7;          // channel group: ch0 = g*16
  const int pxg = tid >> 3;       // pixel group: wo0 = pxg*4
  floatx4 acc[4][4];
  {
    const floatx4* bp = (const floatx4*)&bS[g*16];
    floatx4 b0 = bp[0], b1 = bp[1], b2 = bp[2], b3 = bp[3];
#pragma unroll
    for (int px=0;px<4;px++) { acc[px][0]=b0; acc[px][1]=b1; acc[px][2]=b2; acc[px][3]=b3; }
  }
#pragma unroll
  for (int c=0;c<3;c++)
#pragma unroll
    for (int kh=0;kh<4;kh++) {
      const float* row = &inS[(c*4+kh)*260];
#pragma unroll
      for (int kw=0;kw<4;kw++) {
        const int tap = c*16 + kh*4 + kw;
        const floatx4* wp = (const floatx4*)&wS[tap*128 + g*16];
        floatx4 w0 = wp[0], w1 = wp[1], w2 = wp[2], w3 = wp[3];
#pragma unroll
        for (int px=0;px<4;px++) {
          float xv = row[((pxg*4 + px) << 1) + kw];
          acc[px][0] += xv*w0; acc[px][1] += xv*w1;
          acc[px][2] += xv*w2; acc[px][3] += xv*w3;
        }
      }
    }

  u16* ob = outI + b*IS130 + ho*RS130;
#pragma unroll
  for (int px=0;px<4;px++) {
    const int wo = pxg*4 + px;
    u16* p = ob + wo*128 + g*16;
#pragma unroll
    for (int k=0;k<4;k++) {
      union { u16 u[4]; uint2 v2; } pk;
#pragma unroll
      for (int j=0;j<4;j++) pk.u[j] = f2bf(fmaxf(acc[px][k][j], 0.f));
      *(uint2*)(p + k*4) = pk.v2;
    }
  }
}

// ---------------- dt2 GEMM: cols[p][48] = in[p][128ch] . Wb[48][128]^T, MFMA, no LDS ----------------
__global__ __launch_bounds__(256) void dt2_gemm(
    const u16* __restrict__ inI, const u16* __restrict__ Wb,   // Wb: [n48][k128] bf16
    float* __restrict__ cols)
{
  const int tid = threadIdx.x;
  const int w = tid >> 6, lane = tid & 63, quad = lane >> 4, l16 = lane & 15;
  const int pixBase = blockIdx.x*256 + w*64;

  // B fragments: 3 n-tiles x 4 k-chunks, from L2-resident 12KB table
  short8 Bf[3][4];
#pragma unroll
  for (int nt=0; nt<3; nt++)
#pragma unroll
    for (int kc=0; kc<4; kc++)
      Bf[nt][kc] = *(const short8*)(Wb + (nt*16 + l16)*128 + kc*32 + quad*8);

  // A base addresses (per m-subtile; this lane's pixel row)
  const u16* ap[4];
#pragma unroll
  for (int ms=0; ms<4; ms++) {
    int p = pixBase + ms*16 + l16;
    int b = p >> 14, rem = p & 16383;
    ap[ms] = inI + b*IS130 + (rem >> 7)*RS130 + (rem & 127)*128;
  }

  floatx4 zz = {0.f,0.f,0.f,0.f};
  floatx4 acc[4][3];
#pragma unroll
  for (int ms=0; ms<4; ms++)
#pragma unroll
    for (int nt=0; nt<3; nt++) acc[ms][nt] = zz;

#pragma unroll
  for (int kc=0; kc<4; kc++) {
#pragma unroll
    for (int ms=0; ms<4; ms++) {
      short8 a = *(const short8*)(ap[ms] + kc*32 + quad*8);
#pragma unroll
      for (int nt=0; nt<3; nt++)
        acc[ms][nt] = __builtin_amdgcn_mfma_f32_16x16x32_bf16(a, Bf[nt][kc], acc[ms][nt], 0, 0, 0);
    }
  }

#pragma unroll
  for (int ms=0; ms<4; ms++)
#pragma unroll
    for (int nt=0; nt<3; nt++)
#pragma unroll
      for (int r=0; r<4; r++) {
        int p = pixBase + ms*16 + quad*4 + r;
        cols[(size_t)p*48 + nt*16 + l16] = acc[ms][nt][r];
      }
}

// ---------------- dt2 gather: col2im (4 taps x 3 ch per output pixel) + bias -> NCHW fp32 ----------------
__global__ __launch_bounds__(256) void dt2_gather(
    const float* __restrict__ cols, const float* __restrict__ bias,
    float* __restrict__ xhat)
{
  int id = blockIdx.x*256 + threadIdx.x;    // 16*256*256
  int b = id >> 16, rem = id & 65535;
  int ho = rem >> 8, wo = rem & 255;
  const int ph = ho & 1, pw = wo & 1;
  const int hi0 = ph ? ((ho+1)>>1) : (ho>>1);
  const int kh0 = ph ? 0 : 1;
  const int wi0 = pw ? ((wo+1)>>1) : (wo>>1);
  const int kw0 = pw ? 0 : 1;
  float a0 = bias[0], a1 = bias[1], a2 = bias[2];
#pragma unroll
  for (int th=0; th<2; th++) {
    const int hi = hi0 - th;
    if ((unsigned)hi >= 128u) continue;
    const int kh = kh0 + 2*th;
#pragma unroll
    for (int tw=0; tw<2; tw++) {
      const int wi = wi0 - tw;
      if ((unsigned)wi >= 128u) continue;
      const int kw = kw0 + 2*tw;
      const float* r = cols + (size_t)((b << 14) + (hi << 7) + wi)*48 + (kh*4 + kw);
      a0 += r[0]; a1 += r[16]; a2 += r[32];
    }
  }
  const int ob = ((b*3) << 16) + (ho << 8) + wo;
  xhat[ob]          = a0;
  xhat[ob + 65536]  = a1;
  xhat[ob + 131072] = a2;
}

// =====================================================================================
extern "C" void kernel_launch(void* const* d_in, const int* in_sizes, int n_in,
                              void* d_out, int out_size, void* d_ws, size_t ws_size,
                              hipStream_t stream)
{
  const float* x     = (const float*)d_in[0];
  const float* e1w   = (const float*)d_in[1];
  const float* e1b   = (const float*)d_in[2];
  const float* e2w   = (const float*)d_in[3];
  const float* e2b   = (const float*)d_in[4];
  const float* e3w   = (const float*)d_in[5];
  const float* e3b   = (const float*)d_in[6];
  const float* er1aw = (const float*)d_in[7];
  const float* er1ab = (const float*)d_in[8];
  const float* er1bw = (const float*)d_in[9];
  const float* er1bb = (const float*)d_in[10];
  const float* er2aw = (const float*)d_in[11];
  const float* er2ab = (const float*)d_in[12];
  const float* er2bw = (const float*)d_in[13];
  const float* er2bb = (const float*)d_in[14];
  const float* cb    = (const float*)d_in[15];
  const float* d1w   = (const float*)d_in[16];
  const float* d1b   = (const float*)d_in[17];
  const float* dr1aw = (const float*)d_in[18];
  const float* dr1ab = (const float*)d_in[19];
  const float* dr1bw = (const float*)d_in[20];
  const float* dr1bb = (const float*)d_in[21];
  const float* dr2aw = (const float*)d_in[22];
  const float* dr2ab = (const float*)d_in[23];
  const float* dr2bw = (const float*)d_in[24];
  const float* dr2bb = (const float*)d_in[25];
  const float* dt1w  = (const float*)d_in[26];
  const float* dt1b  = (const float*)d_in[27];
  const float* dt2w  = (const float*)d_in[28];
  const float* dt2b  = (const float*)d_in[29];
  float* out = (float*)d_out;

  char* ws = (char*)d_ws;
  size_t off = 0;
  auto alloc = [&](size_t bytes) -> void* {
    void* r = ws + off; off += (bytes + 255) & ~(size_t)255; return r;
  };

  u16* BIG = (u16*)alloc((size_t)IS130*16*2);      // e1-out, later dt1-out (130x130 halo)
  u16* S[4];
  for (int i=0;i<4;i++) S[i] = (u16*)alloc((size_t)IS66*16*2);
  unsigned long long* minb = (unsigned long long*)alloc((size_t)65536*8);
  u16* W_e2 = (u16*)alloc(262144*2);
  u16* W9[6]; for (int i=0;i<6;i++) W9[i] = (u16*)alloc(147456*2);
  u16* W1[4]; for (int i=0;i<4;i++) W1[i] = (u16*)alloc(16384*2);
  u16* Wdt1 = (u16*)alloc(262144*2);
  u16* cbBF = (u16*)alloc(65536*2);
  float* cbn = (float*)alloc(512*4);
  float* wsE1 = (float*)alloc(6144*4);
  u16* Wb48 = (u16*)alloc(6144*2);

  u16* BIGi = BIG + RS130 + 128;
  u16* Si[4];
  for (int i=0;i<4;i++) Si[i] = S[i] + RS66 + 128;
  u16* zeBFc = S[1];          // compact [p][c] VQ A-matrix reuses S1 (t2 dead by then)
  float* cols = (float*)S[1]; // dt2 cols fp32 50.3MB spans S1..S3 (all dead by dt2 time)

  // 1. zero halos + init minb (ws is re-poisoned before every timed launch)
  zero_halos<<<1812, 256, 0, stream>>>(BIG, S[0], S[1], S[2], S[3], minb);

  // 2. weights
  WTab wtab; int ne = 0; wtab.cum[0] = 0;
  auto addw = [&](const float* s, u16* d, int O, int I, int T, int m, int items) {
    wtab.e[ne] = {s, d, O, I, T, m};
    wtab.cum[ne+1] = wtab.cum[ne] + items; ne++;
  };
  addw(e2w,   W_e2, 128,128,16,0, 262144);
  addw(e3w,   W9[0],128,128, 9,0, 147456);
  addw(er1aw, W9[1],128,128, 9,0, 147456);
  addw(er2aw, W9[2],128,128, 9,0, 147456);
  addw(d1w,   W9[3],128,128, 9,0, 147456);
  addw(dr1aw, W9[4],128,128, 9,0, 147456);
  addw(dr2aw, W9[5],128,128, 9,0, 147456);
  addw(er1bw, W1[0],128,128, 1,0, 16384);
  addw(er2bw, W1[1],128,128, 1,0, 16384);
  addw(dr1bw, W1[2],128,128, 1,0, 16384);
  addw(dr2bw, W1[3],128,128, 1,0, 16384);
  addw(dt1w,  Wdt1, 0,0,0,1, 262144);
  addw(cb,    cbBF, 0,0,0,2, 65536);
  addw(cb,    (u16*)cbn, 0,0,0,3, 512);
  addw(e1w,   (u16*)wsE1, 0,0,0,4, 6144);
  addw(dt2w,  Wb48, 0,0,0,5, 6144);
  wtab.n = ne;
  prep_w<<<(wtab.cum[ne] + 255)/256, 256, 0, stream>>>(wtab);

  // 3. e1 (row-tiled direct fp32)
  conv_e1<<<2048, 256, 0, stream>>>(x, wsE1, e1b, BIGi);

  // taps
  Taps t16; t16.n = 16; t16.dh2 = 0; t16.dw2 = 0;
  for (int t=0;t<16;t++) { t16.dh2 |= (unsigned)(t>>2) << (2*t); t16.dw2 |= (unsigned)(t&3) << (2*t); }
  Taps t9; t9.n = 9; t9.dh2 = 0; t9.dw2 = 0;
  for (int t=0;t<9;t++) { t9.dh2 |= (unsigned)(t/3) << (2*t); t9.dw2 |= (unsigned)(t%3) << (2*t); }
  Taps t1x; t1x.n = 1; t1x.dh2 = 1; t1x.dw2 = 1;
  Taps tc[4];
  for (int cls=0; cls<4; ++cls) {
    int po = cls >> 1, pw = cls & 1;
    tc[cls].n = 4; tc[cls].dh2 = 0; tc[cls].dw2 = 0;
    for (int tt=0; tt<4; ++tt) {
      int th = tt >> 1, tw = tt & 1;
      int dh = po ? (th ? 0 : 1) : (th ? -1 : 0);
      int dw = pw ? (tw ? 0 : 1) : (tw ? -1 : 0);
      tc[cls].dh2 |= (unsigned)(dh+1) << (2*tt);
      tc[cls].dw2 |= (unsigned)(dw+1) << (2*tt);
    }
  }

  auto conv = [&](const u16* in_, int iRS, int iIS, int si,
                  const u16* w_, const float* b_, Taps tp,
                  u16* o_, int oRS, int oIS, int so, int oh, int ow,
                  const u16* r_, u16* o2, int rl, float* zf, u16* zb) {
    conv_mfma<<<512, 256, 0, stream>>>(in_, iRS, iIS, si, w_, b_, tp,
                                       o_, oRS, oIS, so, oh, ow, r_, o2, rl, zf, zb);
  };

  // encoder
  conv(BIGi, RS130, IS130, 2, W_e2, e2b, t16, Si[0], RS66, IS66, 1,0,0, nullptr, nullptr, 1, nullptr, nullptr); // e2 -> S0 (relu)
  conv(Si[0], RS66, IS66, 1, W9[0], e3b, t9, Si[1], RS66, IS66, 1,0,0, nullptr, Si[2], 0, nullptr, nullptr);    // e3 -> t2=S1, relu->S2
  conv(Si[2], RS66, IS66, 1, W9[1], er1ab, t9, Si[0], RS66, IS66, 1,0,0, nullptr, nullptr, 1, nullptr, nullptr);// er1a -> S0 (relu)
  conv(Si[0], RS66, IS66, 1, W1[0], er1bb, t1x, Si[3], RS66, IS66, 1,0,0, Si[1], Si[2], 0, nullptr, nullptr);   // er1b(+t2) -> t4=S3, relu->S2
  conv(Si[2], RS66, IS66, 1, W9[2], er2ab, t9, Si[0], RS66, IS66, 1,0,0, nullptr, nullptr, 1, nullptr, nullptr);// er2a -> S0 (relu)
  conv(Si[0], RS66, IS66, 1, W1[1], er2bb, t1x, nullptr, RS66, IS66, 1,0,0, Si[3], nullptr, 0,
       out + 3145728, zeBFc);                                                                                   // er2b(+t4) -> ze (direct NCHW) + compact bf16

  // VQ
  vq_score<<<dim3(512,4), 256, 0, stream>>>(zeBFc, cbBF, cbn, minb);
  zq_out_k<<<32768, 256, 0, stream>>>(minb, cb, out + 11534336, Si[2]);   // zq fp32 out + bf16 -> S2

  // decoder
  conv(Si[2], RS66, IS66, 1, W9[3], d1b, t9, Si[0], RS66, IS66, 1,0,0, nullptr, Si[1], 0, nullptr, nullptr);    // d1 -> g1=S0, relu->S1
  conv(Si[1], RS66, IS66, 1, W9[4], dr1ab, t9, Si[2], RS66, IS66, 1,0,0, nullptr, nullptr, 1, nullptr, nullptr);// dr1a -> S2 (relu)
  conv(Si[2], RS66, IS66, 1, W1[2], dr1bb, t1x, Si[3], RS66, IS66, 1,0,0, Si[0], Si[1], 0, nullptr, nullptr);   // dr1b(+g1) -> g2=S3, relu->S1
  conv(Si[1], RS66, IS66, 1, W9[5], dr2ab, t9, Si[2], RS66, IS66, 1,0,0, nullptr, nullptr, 1, nullptr, nullptr);// dr2a -> S2 (relu)
  conv(Si[2], RS66, IS66, 1, W1[3], dr2bb, t1x, Si[0], RS66, IS66, 1,0,0, Si[3], nullptr, 0, nullptr, nullptr); // dr2b(+g2) -> g3=S0

  // dt1: convT as 4 parity-class stride-1 convs, relu
  for (int cls=0; cls<4; ++cls) {
    int po = cls >> 1, pw = cls & 1;
    conv(Si[0], RS66, IS66, 1, Wdt1 + cls*65536, dt1b, tc[cls],
         BIGi, RS130, IS130, 2, po, pw, nullptr, nullptr, 1, nullptr, nullptr);
  }

  // dt2: cols GEMM (MFMA) + col2im gather
  dt2_gemm<<<1024, 256, 0, stream>>>(BIGi, Wb48, cols);
  dt2_gather<<<4096, 256, 0, stream>>>(cols, dt2b, out);
}

// Round 5
// 747.177 us; speedup vs baseline: 1.8656x; 1.0653x over previous
//
#include <hip/hip_runtime.h>
#include <stdint.h>

typedef unsigned short u16;
typedef __attribute__((ext_vector_type(8))) short short8;
typedef __attribute__((ext_vector_type(4))) float floatx4;

#define RS66  (66*128)
#define IS66  (66*66*128)
#define RS130 (130*128)
#define IS130 (130*130*128)

__device__ __forceinline__ float bf2f(u16 h) {
  union { unsigned u; float f; } v; v.u = ((unsigned)h) << 16; return v.f;
}
__device__ __forceinline__ u16 f2bf(float f) {
  union { float f; unsigned u; } v; v.f = f;
  unsigned r = v.u + 0x7FFFu + ((v.u >> 16) & 1u);
  return (u16)(r >> 16);
}
__device__ __forceinline__ void gl_lds16(const void* g, void* l) {
  __builtin_amdgcn_global_load_lds(
      (const __attribute__((address_space(1))) void*)(uintptr_t)g,
      (__attribute__((address_space(3))) void*)(uintptr_t)l, 16, 0, 0);
}
__device__ __forceinline__ unsigned fkey(float f) {
  unsigned u = __float_as_uint(f);
  return (u & 0x80000000u) ? ~u : (u | 0x80000000u);
}

struct Taps { int n; unsigned dh2; unsigned dw2; };  // 2-bit packed (d+1); multi: 8 bits/class

// ---------------- MFMA implicit-GEMM conv: tile 128 pixels x 128 outch, K=taps*128 ----------------
__global__ __launch_bounds__(256) void conv_mfma(
    const u16* __restrict__ in, int inRS, int inIS, int si,
    const u16* __restrict__ wt, const float* __restrict__ bias, Taps tp,
    u16* __restrict__ out, int outRS, int outIS, int so, int oh0, int ow0,
    const u16* __restrict__ res, u16* __restrict__ out2, int reluMain,
    float* __restrict__ zeFc, u16* __restrict__ zeBFc, int multi)
{
  __shared__ u16 lA[4096];
  __shared__ u16 lB[4096];
  const int tid = threadIdx.x;
  const int w = tid >> 6, lane = tid & 63, quad = lane >> 4, l16 = lane & 15;
  const int wm = w >> 1, wn = w & 1;
  const int q = tid & 3, p0 = tid >> 2;
  const int blockM = blockIdx.x << 7;

  unsigned dh2 = tp.dh2, dw2 = tp.dw2;
  if (multi) {
    const int cls = blockIdx.y;
    dh2 = (tp.dh2 >> (8*cls)) & 0xffu;
    dw2 = (tp.dw2 >> (8*cls)) & 0xffu;
    wt += cls << 16;
    oh0 = cls >> 1; ow0 = cls & 1;
  }

  const int pg0 = blockM + p0, pg1 = pg0 + 64;
  const int b0 = pg0 >> 12, mo0 = (pg0 >> 6) & 63, no0 = pg0 & 63;
  const int b1 = pg1 >> 12, mo1 = (pg1 >> 6) & 63, no1 = pg1 & 63;
  const u16* gA0 = in + b0*inIS + si*mo0*inRS + si*no0*128 + q*8;
  const u16* gA1 = in + b1*inIS + si*mo1*inRS + si*no1*128 + q*8;
  const u16* gB0 = wt + p0*128 + q*8;
  const u16* gB1 = gB0 + 64*128;
  u16* lsA0 = lA + w*512; u16* lsA1 = lsA0 + 2048;
  u16* lsB0 = lB + w*512; u16* lsB1 = lsB0 + 2048;

  floatx4 zz = {0.f,0.f,0.f,0.f};
  floatx4 acc[4][4];
#pragma unroll
  for (int i=0;i<4;i++)
#pragma unroll
    for (int j=0;j<4;j++) acc[i][j] = zz;

  for (int t = 0; t < tp.n; ++t) {
    const int dh = (int)((dh2 >> (2*t)) & 3u) - 1;
    const int dw = (int)((dw2 >> (2*t)) & 3u) - 1;
    const int aoff = dh*inRS + dw*128;
    const int boff = t << 14;
#pragma unroll
    for (int kc = 0; kc < 4; ++kc) {
      __syncthreads();
      gl_lds16(gA0 + aoff + kc*32, lsA0);
      gl_lds16(gA1 + aoff + kc*32, lsA1);
      gl_lds16(gB0 + boff + kc*32, lsB0);
      gl_lds16(gB1 + boff + kc*32, lsB1);
      __syncthreads();
      short8 af[4], bfr[4];
#pragma unroll
      for (int s=0;s<4;s++) af[s]  = *(const short8*)&lA[(wm*64 + s*16 + l16)*32 + quad*8];
#pragma unroll
      for (int s=0;s<4;s++) bfr[s] = *(const short8*)&lB[(wn*64 + s*16 + l16)*32 + quad*8];
#pragma unroll
      for (int i=0;i<4;i++)
#pragma unroll
        for (int j=0;j<4;j++)
          acc[i][j] = __builtin_amdgcn_mfma_f32_16x16x32_bf16(af[i], bfr[j], acc[i][j], 0, 0, 0);
    }
  }

  float bv[4];
#pragma unroll
  for (int j=0;j<4;j++) bv[j] = bias[wn*64 + j*16 + l16];

#pragma unroll
  for (int i=0;i<4;i++) {
#pragma unroll
    for (int r=0;r<4;r++) {
      const int p = blockM + wm*64 + i*16 + quad*4 + r;
      const int bb = p >> 12, mo = (p >> 6) & 63, no = p & 63;
      const int ob = bb*outIS + (so*mo + oh0)*outRS + (so*no + ow0)*128;
#pragma unroll
      for (int j=0;j<4;j++) {
        const int n = wn*64 + j*16 + l16;
        float v = acc[i][j][r] + bv[j];
        if (res)  v += bf2f(res[ob + n]);
        if (out)  out[ob + n]  = f2bf(reluMain ? fmaxf(v, 0.f) : v);
        if (out2) out2[ob + n] = f2bf(fmaxf(v, 0.f));
        if (zeFc) {
          zeFc[((size_t)p << 7) + n] = v;          // compact fp32 (coalesced)
          zeBFc[((size_t)p << 7) + n] = f2bf(v);   // compact bf16 for VQ
        }
      }
    }
  }
}

// ---------------- VQ: scores = ze . cb^T, per-pixel argmin via packed atomicMin ----------------
__global__ __launch_bounds__(256) void vq_score(
    const u16* __restrict__ zeBF, const u16* __restrict__ cbBF,
    const float* __restrict__ cbn, unsigned long long* __restrict__ minbuf)
{
  __shared__ u16 lA[4096];
  __shared__ u16 lB[4096];
  const int tid = threadIdx.x;
  const int w = tid >> 6, lane = tid & 63, quad = lane >> 4, l16 = lane & 15;
  const int wm = w >> 1, wn = w & 1;
  const int q = tid & 3, p0 = tid >> 2;
  const int blockM = blockIdx.x << 7;
  const int nb = blockIdx.y;
  const u16* gA0 = zeBF + ((blockM + p0) << 7) + q*8;
  const u16* gA1 = gA0 + (64 << 7);
  const u16* gB0 = cbBF + ((nb*128 + p0) << 7) + q*8;
  const u16* gB1 = gB0 + (64 << 7);
  u16* lsA0 = lA + w*512; u16* lsA1 = lsA0 + 2048;
  u16* lsB0 = lB + w*512; u16* lsB1 = lsB0 + 2048;

  floatx4 zz = {0.f,0.f,0.f,0.f};
  floatx4 acc[4][4];
#pragma unroll
  for (int i=0;i<4;i++)
#pragma unroll
    for (int j=0;j<4;j++) acc[i][j] = zz;

#pragma unroll
  for (int kc = 0; kc < 4; ++kc) {
    __syncthreads();
    gl_lds16(gA0 + kc*32, lsA0);
    gl_lds16(gA1 + kc*32, lsA1);
    gl_lds16(gB0 + kc*32, lsB0);
    gl_lds16(gB1 + kc*32, lsB1);
    __syncthreads();
    short8 af[4], bfr[4];
#pragma unroll
    for (int s=0;s<4;s++) af[s]  = *(const short8*)&lA[(wm*64 + s*16 + l16)*32 + quad*8];
#pragma unroll
    for (int s=0;s<4;s++) bfr[s] = *(const short8*)&lB[(wn*64 + s*16 + l16)*32 + quad*8];
#pragma unroll
    for (int i=0;i<4;i++)
#pragma unroll
      for (int j=0;j<4;j++)
        acc[i][j] = __builtin_amdgcn_mfma_f32_16x16x32_bf16(af[i], bfr[j], acc[i][j], 0, 0, 0);
  }

  float cn[4];
#pragma unroll
  for (int j=0;j<4;j++) cn[j] = cbn[nb*128 + wn*64 + j*16 + l16];

#pragma unroll
  for (int i=0;i<4;i++) {
#pragma unroll
    for (int r=0;r<4;r++) {
      const int p = blockM + wm*64 + i*16 + quad*4 + r;
      unsigned long long best = 0xFFFFFFFFFFFFFFFFull;
#pragma unroll
      for (int j=0;j<4;j++) {
        const int n = nb*128 + wn*64 + j*16 + l16;
        float v = cn[j] - acc[i][j][r];       // 0.5||e||^2 - z.e  (same argmin as L2 dist)
        unsigned long long pk = ((unsigned long long)fkey(v) << 32) | (unsigned)n;
        if (pk < best) best = pk;
      }
#pragma unroll
      for (int d=1; d<16; d<<=1) {
        unsigned long long o = __shfl_xor(best, d, 64);
        if (o < best) best = o;
      }
      if (l16 == 0) atomicMin(minbuf + p, best);
    }
  }
}

// ---------------- finalize: ze transpose -> NCHW, zq gather -> NCHW + bf16 NHWC, coalesced ----------------
__global__ __launch_bounds__(256) void finalize(
    const float* __restrict__ zeFc, const unsigned long long* __restrict__ minb,
    const float* __restrict__ cb, float* __restrict__ outZe, float* __restrict__ outZq,
    u16* __restrict__ zqI)
{
  __shared__ float T[64*129];
  __shared__ int ns[64];
  const int tid = threadIdx.x;
  const int P0 = blockIdx.x << 6;                 // 64 pixels, same image & h-row
  const int b = P0 >> 12, hw0 = P0 & 4095;

#pragma unroll
  for (int it=0; it<32; ++it) {                   // coalesced read of ze tile
    int e = it*256 + tid;
    int px = e >> 7, c = e & 127;
    T[px*129 + c] = zeFc[((size_t)P0 << 7) + e];
  }
  if (tid < 64) ns[tid] = (int)(unsigned)(minb[P0 + tid] & 0xFFFFFFFFull);
  __syncthreads();

  float* zeB = outZe + (((size_t)b) << 19) + hw0;
  float* zqB = outZq + (((size_t)b) << 19) + hw0;
  const int h = hw0 >> 6;
  u16* zqIB = zqI + b*IS66 + h*RS66;
#pragma unroll
  for (int it=0; it<32; ++it) {
    const int c = it*4 + (tid >> 6);
    const int px = tid & 63;
    zeB[(c << 12) + px] = T[px*129 + c];          // coalesced 256B per quarter-block
    float v = cb[(ns[px] << 7) + c];              // L2-resident gather
    zqB[(c << 12) + px] = v;
    zqIB[px*128 + c] = f2bf(v);                   // block completes full lines
  }
}

// ---------------- zero halos + init VQ argmin buffer ----------------
__global__ __launch_bounds__(256) void zero_halos(
    u16* big, u16* s0, u16* s1, u16* s2, u16* s3, unsigned long long* minb)
{
  int id = blockIdx.x*256 + threadIdx.x;
  if (id >= 463872) return;
  if (id >= 398336) { minb[id - 398336] = 0xFFFFFFFFFFFFFFFFull; return; }
  u16* base; int H, W;
  if (id < 132096) { base = big; H = 128; W = 128; }
  else {
    id -= 132096;
    int bi = id / 66560;
    id -= bi*66560;
    base = (bi == 0) ? s0 : (bi == 1) ? s1 : (bi == 2) ? s2 : s3;
    H = 64; W = 64;
  }
  int Wp = W+2, Hp = H+2;
  int cv = id & 15; int rest = id >> 4;
  int npx = 2*Wp + 2*H;
  int img = rest / npx; int pix = rest - img*npx;
  int hh, wwp;
  if (pix < Wp) { hh = 0; wwp = pix; }
  else if (pix < 2*Wp) { hh = Hp-1; wwp = pix - Wp; }
  else { int r2 = pix - 2*Wp; hh = 1 + (r2 >> 1); wwp = (r2 & 1) ? (Wp-1) : 0; }
  uint4 zv = {0u,0u,0u,0u};
  *(uint4*)(base + (((size_t)img*Hp + hh)*Wp + wwp)*128 + cv*8) = zv;
}

// ---------------- weight prep ----------------
struct WEnt { const float* src; u16* dst; int O, I, T, mode; };
struct WTab { int n; WEnt e[16]; int cum[17]; };
__global__ __launch_bounds__(256) void prep_w(WTab wt) {
  int id = blockIdx.x*256 + threadIdx.x;
  if (id >= wt.cum[wt.n]) return;
  int k = 0;
  while (id >= wt.cum[k+1]) k++;
  int l = id - wt.cum[k];
  WEnt E = wt.e[k];
  if (E.mode == 0) {
    int i = l % E.I; int rest = l / E.I; int o = rest % E.O; int t = rest / E.O;
    E.dst[l] = f2bf(E.src[(o*E.I + i)*E.T + t]);
  } else if (E.mode == 1) {                 // convT dt1: [I][O][4][4] -> [cls][tt][O][I]
    int i = l & 127, o = (l >> 7) & 127, tt = (l >> 14) & 3, cls = l >> 16;
    int th = tt >> 1, tw = tt & 1, po = cls >> 1, pw = cls & 1;
    int kh = po ? (th ? 2 : 0) : (th ? 3 : 1);
    int kw = pw ? (tw ? 2 : 0) : (tw ? 3 : 1);
    E.dst[l] = f2bf(E.src[((i*128 + o)*4 + kh)*4 + kw]);
  } else if (E.mode == 2) {                 // codebook cast
    E.dst[l] = f2bf(E.src[l]);
  } else if (E.mode == 3) {                 // codebook 0.5*||e||^2
    float s = 0.f; const float* r = E.src + l*128;
    for (int c=0;c<128;c++) s += r[c]*r[c];
    ((float*)E.dst)[l] = 0.5f*s;
  } else if (E.mode == 4) {                 // e1 weights fp32 [o][48] -> [tap][o]
    int o = l & 127, tap = l >> 7;
    ((float*)E.dst)[l] = E.src[o*48 + tap];
  } else {                                  // mode 5: dt2 [c128][o3][4][4] -> bf16 [n48][c128]
    int c = l & 127, n = l >> 7;            // n = o*16 + kh*4+kw
    int o = n >> 4, kk = n & 15;
    E.dst[l] = f2bf(E.src[c*48 + o*16 + kk]);
  }
}

// ---------------- e1: 3->128, k4 s2 p1, row-tiled direct fp32, relu -> bf16 NHWC halo ----------------
__global__ __launch_bounds__(256) void conv_e1(
    const float* __restrict__ x, const float* __restrict__ wT,   // wT: [tap48][o128] fp32
    const float* __restrict__ bias, u16* __restrict__ outI)
{
  __shared__ float inS[12*260];
  __shared__ float wS[48*128];
  __shared__ float bS[128];
  const int tid = threadIdx.x;
  const int b = blockIdx.x >> 7, ho = blockIdx.x & 127;

  for (int l = tid; l < 1536; l += 256)
    ((float4*)wS)[l] = ((const float4*)wT)[l];
  if (tid < 128) bS[tid] = bias[tid];
  for (int l = tid; l < 3120; l += 256) {
    int col = l % 260; int rest = l / 260;
    int kh = rest & 3, c = rest >> 2;
    int hi = 2*ho + kh - 1, wi = col - 1;
    float v = 0.f;
    if ((unsigned)hi < 256u && (unsigned)wi < 256u)
      v = x[((b*3 + c) << 16) + (hi << 8) + wi];
    inS[rest*260 + col] = v;
  }
  __syncthreads();

  const int g = tid & 7;
  const int pxg = tid >> 3;
  floatx4 acc[4][4];
  {
    const floatx4* bp = (const floatx4*)&bS[g*16];
    floatx4 b0 = bp[0], b1 = bp[1], b2 = bp[2], b3 = bp[3];
#pragma unroll
    for (int px=0;px<4;px++) { acc[px][0]=b0; acc[px][1]=b1; acc[px][2]=b2; acc[px][3]=b3; }
  }
#pragma unroll
  for (int c=0;c<3;c++)
#pragma unroll
    for (int kh=0;kh<4;kh++) {
      const float* row = &inS[(c*4+kh)*260];
#pragma unroll
      for (int kw=0;kw<4;kw++) {
        const int tap = c*16 + kh*4 + kw;
        const floatx4* wp = (const floatx4*)&wS[tap*128 + g*16];
        floatx4 w0 = wp[0], w1 = wp[1], w2 = wp[2], w3 = wp[3];
#pragma unroll
        for (int px=0;px<4;px++) {
          float xv = row[((pxg*4 + px) << 1) + kw];
          acc[px][0] += xv*w0; acc[px][1] += xv*w1;
          acc[px][2] += xv*w2; acc[px][3] += xv*w3;
        }
      }
    }

  u16* ob = outI + b*IS130 + ho*RS130;
#pragma unroll
  for (int px=0;px<4;px++) {
    const int wo = pxg*4 + px;
    u16* p = ob + wo*128 + g*16;
#pragma unroll
    for (int k=0;k<4;k++) {
      union { u16 u[4]; uint2 v2; } pk;
#pragma unroll
      for (int j=0;j<4;j++) pk.u[j] = f2bf(fmaxf(acc[px][k][j], 0.f));
      *(uint2*)(p + k*4) = pk.v2;
    }
  }
}

// ---------------- dt2 GEMM: cols[p][48] = in[p][128ch] . Wb[48][128]^T, MFMA, no LDS ----------------
__global__ __launch_bounds__(256) void dt2_gemm(
    const u16* __restrict__ inI, const u16* __restrict__ Wb,
    float* __restrict__ cols)
{
  const int tid = threadIdx.x;
  const int w = tid >> 6, lane = tid & 63, quad = lane >> 4, l16 = lane & 15;
  const int pixBase = blockIdx.x*256 + w*64;

  short8 Bf[3][4];
#pragma unroll
  for (int nt=0; nt<3; nt++)
#pragma unroll
    for (int kc=0; kc<4; kc++)
      Bf[nt][kc] = *(const short8*)(Wb + (nt*16 + l16)*128 + kc*32 + quad*8);

  const u16* ap[4];
#pragma unroll
  for (int ms=0; ms<4; ms++) {
    int p = pixBase + ms*16 + l16;
    int b = p >> 14, rem = p & 16383;
    ap[ms] = inI + b*IS130 + (rem >> 7)*RS130 + (rem & 127)*128;
  }

  floatx4 zz = {0.f,0.f,0.f,0.f};
  floatx4 acc[4][3];
#pragma unroll
  for (int ms=0; ms<4; ms++)
#pragma unroll
    for (int nt=0; nt<3; nt++) acc[ms][nt] = zz;

#pragma unroll
  for (int kc=0; kc<4; kc++) {
#pragma unroll
    for (int ms=0; ms<4; ms++) {
      short8 a = *(const short8*)(ap[ms] + kc*32 + quad*8);
#pragma unroll
      for (int nt=0; nt<3; nt++)
        acc[ms][nt] = __builtin_amdgcn_mfma_f32_16x16x32_bf16(a, Bf[nt][kc], acc[ms][nt], 0, 0, 0);
    }
  }

#pragma unroll
  for (int ms=0; ms<4; ms++)
#pragma unroll
    for (int nt=0; nt<3; nt++)
#pragma unroll
      for (int r=0; r<4; r++) {
        int p = pixBase + ms*16 + quad*4 + r;
        cols[(size_t)p*48 + nt*16 + l16] = acc[ms][nt][r];
      }
}

// ---------------- dt2 gather: col2im + bias -> NCHW fp32 ----------------
__global__ __launch_bounds__(256) void dt2_gather(
    const float* __restrict__ cols, const float* __restrict__ bias,
    float* __restrict__ xhat)
{
  int id = blockIdx.x*256 + threadIdx.x;
  int b = id >> 16, rem = id & 65535;
  int ho = rem >> 8, wo = rem & 255;
  const int ph = ho & 1, pw = wo & 1;
  const int hi0 = ph ? ((ho+1)>>1) : (ho>>1);
  const int kh0 = ph ? 0 : 1;
  const int wi0 = pw ? ((wo+1)>>1) : (wo>>1);
  const int kw0 = pw ? 0 : 1;
  float a0 = bias[0], a1 = bias[1], a2 = bias[2];
#pragma unroll
  for (int th=0; th<2; th++) {
    const int hi = hi0 - th;
    if ((unsigned)hi >= 128u) continue;
    const int kh = kh0 + 2*th;
#pragma unroll
    for (int tw=0; tw<2; tw++) {
      const int wi = wi0 - tw;
      if ((unsigned)wi >= 128u) continue;
      const int kw = kw0 + 2*tw;
      const float* r = cols + (size_t)((b << 14) + (hi << 7) + wi)*48 + (kh*4 + kw);
      a0 += r[0]; a1 += r[16]; a2 += r[32];
    }
  }
  const int ob = ((b*3) << 16) + (ho << 8) + wo;
  xhat[ob]          = a0;
  xhat[ob + 65536]  = a1;
  xhat[ob + 131072] = a2;
}

// =====================================================================================
extern "C" void kernel_launch(void* const* d_in, const int* in_sizes, int n_in,
                              void* d_out, int out_size, void* d_ws, size_t ws_size,
                              hipStream_t stream)
{
  const float* x     = (const float*)d_in[0];
  const float* e1w   = (const float*)d_in[1];
  const float* e1b   = (const float*)d_in[2];
  const float* e2w   = (const float*)d_in[3];
  const float* e2b   = (const float*)d_in[4];
  const float* e3w   = (const float*)d_in[5];
  const float* e3b   = (const float*)d_in[6];
  const float* er1aw = (const float*)d_in[7];
  const float* er1ab = (const float*)d_in[8];
  const float* er1bw = (const float*)d_in[9];
  const float* er1bb = (const float*)d_in[10];
  const float* er2aw = (const float*)d_in[11];
  const float* er2ab = (const float*)d_in[12];
  const float* er2bw = (const float*)d_in[13];
  const float* er2bb = (const float*)d_in[14];
  const float* cb    = (const float*)d_in[15];
  const float* d1w   = (const float*)d_in[16];
  const float* d1b   = (const float*)d_in[17];
  const float* dr1aw = (const float*)d_in[18];
  const float* dr1ab = (const float*)d_in[19];
  const float* dr1bw = (const float*)d_in[20];
  const float* dr1bb = (const float*)d_in[21];
  const float* dr2aw = (const float*)d_in[22];
  const float* dr2ab = (const float*)d_in[23];
  const float* dr2bw = (const float*)d_in[24];
  const float* dr2bb = (const float*)d_in[25];
  const float* dt1w  = (const float*)d_in[26];
  const float* dt1b  = (const float*)d_in[27];
  const float* dt2w  = (const float*)d_in[28];
  const float* dt2b  = (const float*)d_in[29];
  float* out = (float*)d_out;

  char* ws = (char*)d_ws;
  size_t off = 0;
  auto alloc = [&](size_t bytes) -> void* {
    void* r = ws + off; off += (bytes + 255) & ~(size_t)255; return r;
  };

  u16* BIG = (u16*)alloc((size_t)IS130*16*2);      // e1-out / ze-compact / dt1-out
  u16* S[4];
  for (int i=0;i<4;i++) S[i] = (u16*)alloc((size_t)IS66*16*2);
  unsigned long long* minb = (unsigned long long*)alloc((size_t)65536*8);
  u16* W_e2 = (u16*)alloc(262144*2);
  u16* W9[6]; for (int i=0;i<6;i++) W9[i] = (u16*)alloc(147456*2);
  u16* W1[4]; for (int i=0;i<4;i++) W1[i] = (u16*)alloc(16384*2);
  u16* Wdt1 = (u16*)alloc(262144*2);
  u16* cbBF = (u16*)alloc(65536*2);
  float* cbn = (float*)alloc(512*4);
  float* wsE1 = (float*)alloc(6144*4);
  u16* Wb48 = (u16*)alloc(6144*2);

  u16* BIGi = BIG + RS130 + 128;
  u16* Si[4];
  for (int i=0;i<4;i++) Si[i] = S[i] + RS66 + 128;
  u16* zeBFc = S[1];            // compact bf16 ze (VQ A-matrix), S1 dead by er2b
  float* zeFc = (float*)BIG;    // compact fp32 ze (32MB) — BIG free between e2 and dt1
  float* cols = (float*)S[1];   // dt2 cols fp32 spans S1..S3 (dead by dt2 time)

  // 1. zero halos + init minb
  zero_halos<<<1812, 256, 0, stream>>>(BIG, S[0], S[1], S[2], S[3], minb);

  // 2. weights
  WTab wtab; int ne = 0; wtab.cum[0] = 0;
  auto addw = [&](const float* s, u16* d, int O, int I, int T, int m, int items) {
    wtab.e[ne] = {s, d, O, I, T, m};
    wtab.cum[ne+1] = wtab.cum[ne] + items; ne++;
  };
  addw(e2w,   W_e2, 128,128,16,0, 262144);
  addw(e3w,   W9[0],128,128, 9,0, 147456);
  addw(er1aw, W9[1],128,128, 9,0, 147456);
  addw(er2aw, W9[2],128,128, 9,0, 147456);
  addw(d1w,   W9[3],128,128, 9,0, 147456);
  addw(dr1aw, W9[4],128,128, 9,0, 147456);
  addw(dr2aw, W9[5],128,128, 9,0, 147456);
  addw(er1bw, W1[0],128,128, 1,0, 16384);
  addw(er2bw, W1[1],128,128, 1,0, 16384);
  addw(dr1bw, W1[2],128,128, 1,0, 16384);
  addw(dr2bw, W1[3],128,128, 1,0, 16384);
  addw(dt1w,  Wdt1, 0,0,0,1, 262144);
  addw(cb,    cbBF, 0,0,0,2, 65536);
  addw(cb,    (u16*)cbn, 0,0,0,3, 512);
  addw(e1w,   (u16*)wsE1, 0,0,0,4, 6144);
  addw(dt2w,  Wb48, 0,0,0,5, 6144);
  wtab.n = ne;
  prep_w<<<(wtab.cum[ne] + 255)/256, 256, 0, stream>>>(wtab);

  // 3. e1
  conv_e1<<<2048, 256, 0, stream>>>(x, wsE1, e1b, BIGi);

  // taps
  Taps t16; t16.n = 16; t16.dh2 = 0; t16.dw2 = 0;
  for (int t=0;t<16;t++) { t16.dh2 |= (unsigned)(t>>2) << (2*t); t16.dw2 |= (unsigned)(t&3) << (2*t); }
  Taps t9; t9.n = 9; t9.dh2 = 0; t9.dw2 = 0;
  for (int t=0;t<9;t++) { t9.dh2 |= (unsigned)(t/3) << (2*t); t9.dw2 |= (unsigned)(t%3) << (2*t); }
  Taps t1x; t1x.n = 1; t1x.dh2 = 1; t1x.dw2 = 1;
  Taps tcm; tcm.n = 4; tcm.dh2 = 0; tcm.dw2 = 0;   // packed: 8 bits per class
  for (int cls=0; cls<4; ++cls) {
    int po = cls >> 1, pw = cls & 1;
    for (int tt=0; tt<4; ++tt) {
      int th = tt >> 1, tw = tt & 1;
      int dh = po ? (th ? 0 : 1) : (th ? -1 : 0);
      int dw = pw ? (tw ? 0 : 1) : (tw ? -1 : 0);
      tcm.dh2 |= (unsigned)(dh+1) << (8*cls + 2*tt);
      tcm.dw2 |= (unsigned)(dw+1) << (8*cls + 2*tt);
    }
  }

  auto conv = [&](const u16* in_, int iRS, int iIS, int si,
                  const u16* w_, const float* b_, Taps tp,
                  u16* o_, int oRS, int oIS, int so, int oh, int ow,
                  const u16* r_, u16* o2, int rl, float* zf, u16* zb) {
    conv_mfma<<<512, 256, 0, stream>>>(in_, iRS, iIS, si, w_, b_, tp,
                                       o_, oRS, oIS, so, oh, ow, r_, o2, rl, zf, zb, 0);
  };

  // encoder
  conv(BIGi, RS130, IS130, 2, W_e2, e2b, t16, Si[0], RS66, IS66, 1,0,0, nullptr, nullptr, 1, nullptr, nullptr); // e2 -> S0 (relu)
  conv(Si[0], RS66, IS66, 1, W9[0], e3b, t9, Si[1], RS66, IS66, 1,0,0, nullptr, Si[2], 0, nullptr, nullptr);    // e3 -> t2=S1, relu->S2
  conv(Si[2], RS66, IS66, 1, W9[1], er1ab, t9, Si[0], RS66, IS66, 1,0,0, nullptr, nullptr, 1, nullptr, nullptr);// er1a -> S0 (relu)
  conv(Si[0], RS66, IS66, 1, W1[0], er1bb, t1x, Si[3], RS66, IS66, 1,0,0, Si[1], Si[2], 0, nullptr, nullptr);   // er1b(+t2) -> t4=S3, relu->S2
  conv(Si[2], RS66, IS66, 1, W9[2], er2ab, t9, Si[0], RS66, IS66, 1,0,0, nullptr, nullptr, 1, nullptr, nullptr);// er2a -> S0 (relu)
  conv(Si[0], RS66, IS66, 1, W1[1], er2bb, t1x, nullptr, RS66, IS66, 1,0,0, Si[3], nullptr, 0, zeFc, zeBFc);    // er2b(+t4) -> ze compact (fp32+bf16)

  // VQ + outputs
  vq_score<<<dim3(512,4), 256, 0, stream>>>(zeBFc, cbBF, cbn, minb);
  finalize<<<1024, 256, 0, stream>>>(zeFc, minb, cb, out + 3145728, out + 11534336, Si[2]);  // zq bf16 -> S2

  // decoder
  conv(Si[2], RS66, IS66, 1, W9[3], d1b, t9, Si[0], RS66, IS66, 1,0,0, nullptr, Si[1], 0, nullptr, nullptr);    // d1 -> g1=S0, relu->S1
  conv(Si[1], RS66, IS66, 1, W9[4], dr1ab, t9, Si[2], RS66, IS66, 1,0,0, nullptr, nullptr, 1, nullptr, nullptr);// dr1a -> S2 (relu)
  conv(Si[2], RS66, IS66, 1, W1[2], dr1bb, t1x, Si[3], RS66, IS66, 1,0,0, Si[0], Si[1], 0, nullptr, nullptr);   // dr1b(+g1) -> g2=S3, relu->S1
  conv(Si[1], RS66, IS66, 1, W9[5], dr2ab, t9, Si[2], RS66, IS66, 1,0,0, nullptr, nullptr, 1, nullptr, nullptr);// dr2a -> S2 (relu)
  conv(Si[2], RS66, IS66, 1, W1[3], dr2bb, t1x, Si[0], RS66, IS66, 1,0,0, Si[3], nullptr, 0, nullptr, nullptr); // dr2b(+g2) -> g3=S0

  // dt1: 4 parity classes in one dispatch (blockIdx.y = cls)
  conv_mfma<<<dim3(512,4), 256, 0, stream>>>(Si[0], RS66, IS66, 1, Wdt1, dt1b, tcm,
                                             BIGi, RS130, IS130, 2, 0, 0,
                                             nullptr, nullptr, 1, nullptr, nullptr, 1);

  // dt2: cols GEMM (MFMA) + col2im gather
  dt2_gemm<<<1024, 256, 0, stream>>>(BIGi, Wb48, cols);
  dt2_gather<<<4096, 256, 0, stream>>>(cols, dt2b, out);
}

// Round 6
// 710.346 us; speedup vs baseline: 1.9623x; 1.0518x over previous
//
#include <hip/hip_runtime.h>
#include <stdint.h>

typedef unsigned short u16;
typedef __attribute__((ext_vector_type(8))) short short8;
typedef __attribute__((ext_vector_type(4))) float floatx4;

#define RS66  (66*128)
#define IS66  (66*66*128)
#define RS130 (130*128)
#define IS130 (130*130*128)

__device__ __forceinline__ float bf2f(u16 h) {
  union { unsigned u; float f; } v; v.u = ((unsigned)h) << 16; return v.f;
}
__device__ __forceinline__ u16 f2bf(float f) {
  union { float f; unsigned u; } v; v.f = f;
  unsigned r = v.u + 0x7FFFu + ((v.u >> 16) & 1u);
  return (u16)(r >> 16);
}
__device__ __forceinline__ void gl_lds16(const void* g, void* l) {
  __builtin_amdgcn_global_load_lds(
      (const __attribute__((address_space(1))) void*)(uintptr_t)g,
      (__attribute__((address_space(3))) void*)(uintptr_t)l, 16, 0, 0);
}
__device__ __forceinline__ unsigned fkey(float f) {
  unsigned u = __float_as_uint(f);
  return (u & 0x80000000u) ? ~u : (u | 0x80000000u);
}

struct Taps { int n; unsigned dh2; unsigned dw2; };  // 2-bit packed (d+1); multi: 8 bits/class

// ---------------- MFMA implicit-GEMM conv: tile 128 px x 128 outch, K=taps*128 ----------------
// Double-buffered K=64 chunks (64KB LDS), XOR-swizzled layout (conflict-free b128 reads),
// one barrier per chunk, prefetch overlaps compute.
__global__ __launch_bounds__(256) void conv_mfma(
    const u16* __restrict__ in, int inRS, int inIS, int si,
    const u16* __restrict__ wt, const float* __restrict__ bias, Taps tp,
    u16* __restrict__ out, int outRS, int outIS, int so, int oh0, int ow0,
    const u16* __restrict__ res, u16* __restrict__ out2, int reluMain,
    float* __restrict__ zeFc, u16* __restrict__ zeBFc, int multi)
{
  __shared__ u16 lA[2][8192];
  __shared__ u16 lB[2][8192];
  const int tid = threadIdx.x;
  const int w = tid >> 6, lane = tid & 63, quad = lane >> 4, l16 = lane & 15;
  const int wm = w >> 1, wn = w & 1;
  const int blockM = blockIdx.x << 7;

  unsigned dh2 = tp.dh2, dw2 = tp.dw2;
  if (multi) {
    const int cls = blockIdx.y;
    dh2 = (tp.dh2 >> (8*cls)) & 0xffu;
    dw2 = (tp.dw2 >> (8*cls)) & 0xffu;
    wt += cls << 16;
    oh0 = cls >> 1; ow0 = cls & 1;
  }

  // staging thread mapping: px = i*32 + (tid>>3); 16B chunk cb_global = (tid&7) ^ ((tid>>3)&7)
  const int swz = (tid & 7) ^ ((tid >> 3) & 7);
  const u16* gA[4]; const u16* gB[4];
#pragma unroll
  for (int i=0;i<4;i++) {
    const int pg = blockM + i*32 + (tid >> 3);
    const int b = pg >> 12, mo = (pg >> 6) & 63, no = pg & 63;
    gA[i] = in + b*inIS + si*mo*inRS + si*no*128 + swz*8;
    gB[i] = wt + (i*32 + (tid >> 3))*128 + swz*8;
  }
  // per (issue, wave) LDS base: (i*32 + w*8) rows of 64 u16
  const int ldsOff = w*512;   // u16 units

  floatx4 zz = {0.f,0.f,0.f,0.f};
  floatx4 acc[4][4];
#pragma unroll
  for (int i=0;i<4;i++)
#pragma unroll
    for (int j=0;j<4;j++) acc[i][j] = zz;

  const int NCH = tp.n << 1;             // chunks of K=64
  auto issue = [&](int ci, int buf) {
    const int t = ci >> 1, kc = ci & 1;
    const int dh = (int)((dh2 >> (2*t)) & 3u) - 1;
    const int dw = (int)((dw2 >> (2*t)) & 3u) - 1;
    const int aoff = dh*inRS + dw*128 + kc*64;
    const int boff = (t << 14) + kc*64;
#pragma unroll
    for (int i=0;i<4;i++) {
      gl_lds16(gA[i] + aoff, &lA[buf][i*2048 + ldsOff]);
      gl_lds16(gB[i] + boff, &lB[buf][i*2048 + ldsOff]);
    }
  };

  issue(0, 0);
  for (int ci = 0; ci < NCH; ++ci) {
    __syncthreads();                      // drains chunk ci's loads (compiler vmcnt before barrier)
    if (ci + 1 < NCH) issue(ci + 1, (ci + 1) & 1);
    const u16* bufA = lA[ci & 1];
    const u16* bufB = lB[ci & 1];
#pragma unroll
    for (int kk=0; kk<2; ++kk) {
      short8 af[4], bfr[4];
#pragma unroll
      for (int s=0;s<4;s++) {
        const int row = wm*64 + s*16 + l16;
        af[s]  = *(const short8*)&bufA[row*64 + (((kk*4 + quad) ^ (l16 & 7)) << 3)];
      }
#pragma unroll
      for (int s=0;s<4;s++) {
        const int row = wn*64 + s*16 + l16;
        bfr[s] = *(const short8*)&bufB[row*64 + (((kk*4 + quad) ^ (l16 & 7)) << 3)];
      }
#pragma unroll
      for (int i=0;i<4;i++)
#pragma unroll
        for (int j=0;j<4;j++)
          acc[i][j] = __builtin_amdgcn_mfma_f32_16x16x32_bf16(af[i], bfr[j], acc[i][j], 0, 0, 0);
    }
  }

  float bv[4];
#pragma unroll
  for (int j=0;j<4;j++) bv[j] = bias[wn*64 + j*16 + l16];

#pragma unroll
  for (int i=0;i<4;i++) {
#pragma unroll
    for (int r=0;r<4;r++) {
      const int p = blockM + wm*64 + i*16 + quad*4 + r;
      const int bb = p >> 12, mo = (p >> 6) & 63, no = p & 63;
      const int ob = bb*outIS + (so*mo + oh0)*outRS + (so*no + ow0)*128;
#pragma unroll
      for (int j=0;j<4;j++) {
        const int n = wn*64 + j*16 + l16;
        float v = acc[i][j][r] + bv[j];
        if (res)  v += bf2f(res[ob + n]);
        if (out)  out[ob + n]  = f2bf(reluMain ? fmaxf(v, 0.f) : v);
        if (out2) out2[ob + n] = f2bf(fmaxf(v, 0.f));
        if (zeFc) {
          zeFc[((size_t)p << 7) + n] = v;          // compact fp32 (coalesced)
          zeBFc[((size_t)p << 7) + n] = f2bf(v);   // compact bf16 for VQ
        }
      }
    }
  }
}

// ---------------- VQ: scores = ze . cb^T, per-pixel argmin via packed atomicMin ----------------
__global__ __launch_bounds__(256) void vq_score(
    const u16* __restrict__ zeBF, const u16* __restrict__ cbBF,
    const float* __restrict__ cbn, unsigned long long* __restrict__ minbuf)
{
  __shared__ u16 lA[4096];
  __shared__ u16 lB[4096];
  const int tid = threadIdx.x;
  const int w = tid >> 6, lane = tid & 63, quad = lane >> 4, l16 = lane & 15;
  const int wm = w >> 1, wn = w & 1;
  const int q = tid & 3, p0 = tid >> 2;
  const int blockM = blockIdx.x << 7;
  const int nb = blockIdx.y;
  const u16* gA0 = zeBF + ((blockM + p0) << 7) + q*8;
  const u16* gA1 = gA0 + (64 << 7);
  const u16* gB0 = cbBF + ((nb*128 + p0) << 7) + q*8;
  const u16* gB1 = gB0 + (64 << 7);
  u16* lsA0 = lA + w*512; u16* lsA1 = lsA0 + 2048;
  u16* lsB0 = lB + w*512; u16* lsB1 = lsB0 + 2048;

  floatx4 zz = {0.f,0.f,0.f,0.f};
  floatx4 acc[4][4];
#pragma unroll
  for (int i=0;i<4;i++)
#pragma unroll
    for (int j=0;j<4;j++) acc[i][j] = zz;

#pragma unroll
  for (int kc = 0; kc < 4; ++kc) {
    __syncthreads();
    gl_lds16(gA0 + kc*32, lsA0);
    gl_lds16(gA1 + kc*32, lsA1);
    gl_lds16(gB0 + kc*32, lsB0);
    gl_lds16(gB1 + kc*32, lsB1);
    __syncthreads();
    short8 af[4], bfr[4];
#pragma unroll
    for (int s=0;s<4;s++) af[s]  = *(const short8*)&lA[(wm*64 + s*16 + l16)*32 + quad*8];
#pragma unroll
    for (int s=0;s<4;s++) bfr[s] = *(const short8*)&lB[(wn*64 + s*16 + l16)*32 + quad*8];
#pragma unroll
    for (int i=0;i<4;i++)
#pragma unroll
      for (int j=0;j<4;j++)
        acc[i][j] = __builtin_amdgcn_mfma_f32_16x16x32_bf16(af[i], bfr[j], acc[i][j], 0, 0, 0);
  }

  float cn[4];
#pragma unroll
  for (int j=0;j<4;j++) cn[j] = cbn[nb*128 + wn*64 + j*16 + l16];

#pragma unroll
  for (int i=0;i<4;i++) {
#pragma unroll
    for (int r=0;r<4;r++) {
      const int p = blockM + wm*64 + i*16 + quad*4 + r;
      unsigned long long best = 0xFFFFFFFFFFFFFFFFull;
#pragma unroll
      for (int j=0;j<4;j++) {
        const int n = nb*128 + wn*64 + j*16 + l16;
        float v = cn[j] - acc[i][j][r];       // 0.5||e||^2 - z.e  (same argmin as L2 dist)
        unsigned long long pk = ((unsigned long long)fkey(v) << 32) | (unsigned)n;
        if (pk < best) best = pk;
      }
#pragma unroll
      for (int d=1; d<16; d<<=1) {
        unsigned long long o = __shfl_xor(best, d, 64);
        if (o < best) best = o;
      }
      if (l16 == 0) atomicMin(minbuf + p, best);
    }
  }
}

// ---------------- finalize: ze transpose -> NCHW, zq gather -> NCHW + bf16 NHWC, coalesced ----------------
__global__ __launch_bounds__(256) void finalize(
    const float* __restrict__ zeFc, const unsigned long long* __restrict__ minb,
    const float* __restrict__ cb, float* __restrict__ outZe, float* __restrict__ outZq,
    u16* __restrict__ zqI)
{
  __shared__ float T[64*129];
  __shared__ int ns[64];
  const int tid = threadIdx.x;
  const int P0 = blockIdx.x << 6;                 // 64 pixels, same image & h-row
  const int b = P0 >> 12, hw0 = P0 & 4095;

#pragma unroll
  for (int it=0; it<32; ++it) {                   // coalesced read of ze tile
    int e = it*256 + tid;
    int px = e >> 7, c = e & 127;
    T[px*129 + c] = zeFc[((size_t)P0 << 7) + e];
  }
  if (tid < 64) ns[tid] = (int)(unsigned)(minb[P0 + tid] & 0xFFFFFFFFull);
  __syncthreads();

  float* zeB = outZe + (((size_t)b) << 19) + hw0;
  float* zqB = outZq + (((size_t)b) << 19) + hw0;
  const int h = hw0 >> 6;
  u16* zqIB = zqI + b*IS66 + h*RS66;
#pragma unroll
  for (int it=0; it<32; ++it) {
    const int c = it*4 + (tid >> 6);
    const int px = tid & 63;
    zeB[(c << 12) + px] = T[px*129 + c];
    float v = cb[(ns[px] << 7) + c];
    zqB[(c << 12) + px] = v;
    zqIB[px*128 + c] = f2bf(v);
  }
}

// ---------------- zero halos + init VQ argmin buffer ----------------
__global__ __launch_bounds__(256) void zero_halos(
    u16* big, u16* s0, u16* s1, u16* s2, u16* s3, unsigned long long* minb)
{
  int id = blockIdx.x*256 + threadIdx.x;
  if (id >= 463872) return;
  if (id >= 398336) { minb[id - 398336] = 0xFFFFFFFFFFFFFFFFull; return; }
  u16* base; int H, W;
  if (id < 132096) { base = big; H = 128; W = 128; }
  else {
    id -= 132096;
    int bi = id / 66560;
    id -= bi*66560;
    base = (bi == 0) ? s0 : (bi == 1) ? s1 : (bi == 2) ? s2 : s3;
    H = 64; W = 64;
  }
  int Wp = W+2, Hp = H+2;
  int cv = id & 15; int rest = id >> 4;
  int npx = 2*Wp + 2*H;
  int img = rest / npx; int pix = rest - img*npx;
  int hh, wwp;
  if (pix < Wp) { hh = 0; wwp = pix; }
  else if (pix < 2*Wp) { hh = Hp-1; wwp = pix - Wp; }
  else { int r2 = pix - 2*Wp; hh = 1 + (r2 >> 1); wwp = (r2 & 1) ? (Wp-1) : 0; }
  uint4 zv = {0u,0u,0u,0u};
  *(uint4*)(base + (((size_t)img*Hp + hh)*Wp + wwp)*128 + cv*8) = zv;
}

// ---------------- weight prep ----------------
struct WEnt { const float* src; u16* dst; int O, I, T, mode; };
struct WTab { int n; WEnt e[16]; int cum[17]; };
__global__ __launch_bounds__(256) void prep_w(WTab wt) {
  int id = blockIdx.x*256 + threadIdx.x;
  if (id >= wt.cum[wt.n]) return;
  int k = 0;
  while (id >= wt.cum[k+1]) k++;
  int l = id - wt.cum[k];
  WEnt E = wt.e[k];
  if (E.mode == 0) {
    int i = l % E.I; int rest = l / E.I; int o = rest % E.O; int t = rest / E.O;
    E.dst[l] = f2bf(E.src[(o*E.I + i)*E.T + t]);
  } else if (E.mode == 1) {                 // convT dt1: [I][O][4][4] -> [cls][tt][O][I]
    int i = l & 127, o = (l >> 7) & 127, tt = (l >> 14) & 3, cls = l >> 16;
    int th = tt >> 1, tw = tt & 1, po = cls >> 1, pw = cls & 1;
    int kh = po ? (th ? 2 : 0) : (th ? 3 : 1);
    int kw = pw ? (tw ? 2 : 0) : (tw ? 3 : 1);
    E.dst[l] = f2bf(E.src[((i*128 + o)*4 + kh)*4 + kw]);
  } else if (E.mode == 2) {                 // codebook cast
    E.dst[l] = f2bf(E.src[l]);
  } else if (E.mode == 3) {                 // codebook 0.5*||e||^2
    float s = 0.f; const float* r = E.src + l*128;
    for (int c=0;c<128;c++) s += r[c]*r[c];
    ((float*)E.dst)[l] = 0.5f*s;
  } else if (E.mode == 4) {                 // e1 weights fp32 [o][48] -> [tap][o]
    int o = l & 127, tap = l >> 7;
    ((float*)E.dst)[l] = E.src[o*48 + tap];
  } else {                                  // mode 5: dt2 [c128][o3][4][4] -> bf16 [n48][c128]
    int c = l & 127, n = l >> 7;            // n = o*16 + kh*4+kw
    int o = n >> 4, kk = n & 15;
    E.dst[l] = f2bf(E.src[c*48 + o*16 + kk]);
  }
}

// ---------------- e1: 3->128, k4 s2 p1, row-tiled direct fp32, relu -> bf16 NHWC halo ----------------
__global__ __launch_bounds__(256) void conv_e1(
    const float* __restrict__ x, const float* __restrict__ wT,   // wT: [tap48][o128] fp32
    const float* __restrict__ bias, u16* __restrict__ outI)
{
  __shared__ float inS[12*260];
  __shared__ float wS[48*128];
  __shared__ float bS[128];
  const int tid = threadIdx.x;
  const int b = blockIdx.x >> 7, ho = blockIdx.x & 127;

  for (int l = tid; l < 1536; l += 256)
    ((float4*)wS)[l] = ((const float4*)wT)[l];
  if (tid < 128) bS[tid] = bias[tid];
  for (int l = tid; l < 3120; l += 256) {
    int col = l % 260; int rest = l / 260;
    int kh = rest & 3, c = rest >> 2;
    int hi = 2*ho + kh - 1, wi = col - 1;
    float v = 0.f;
    if ((unsigned)hi < 256u && (unsigned)wi < 256u)
      v = x[((b*3 + c) << 16) + (hi << 8) + wi];
    inS[rest*260 + col] = v;
  }
  __syncthreads();

  const int g = tid & 7;
  const int pxg = tid >> 3;
  floatx4 acc[4][4];
  {
    const floatx4* bp = (const floatx4*)&bS[g*16];
    floatx4 b0 = bp[0], b1 = bp[1], b2 = bp[2], b3 = bp[3];
#pragma unroll
    for (int px=0;px<4;px++) { acc[px][0]=b0; acc[px][1]=b1; acc[px][2]=b2; acc[px][3]=b3; }
  }
#pragma unroll
  for (int c=0;c<3;c++)
#pragma unroll
    for (int kh=0;kh<4;kh++) {
      const float* row = &inS[(c*4+kh)*260];
#pragma unroll
      for (int kw=0;kw<4;kw++) {
        const int tap = c*16 + kh*4 + kw;
        const floatx4* wp = (const floatx4*)&wS[tap*128 + g*16];
        floatx4 w0 = wp[0], w1 = wp[1], w2 = wp[2], w3 = wp[3];
#pragma unroll
        for (int px=0;px<4;px++) {
          float xv = row[((pxg*4 + px) << 1) + kw];
          acc[px][0] += xv*w0; acc[px][1] += xv*w1;
          acc[px][2] += xv*w2; acc[px][3] += xv*w3;
        }
      }
    }

  u16* ob = outI + b*IS130 + ho*RS130;
#pragma unroll
  for (int px=0;px<4;px++) {
    const int wo = pxg*4 + px;
    u16* p = ob + wo*128 + g*16;
#pragma unroll
    for (int k=0;k<4;k++) {
      union { u16 u[4]; uint2 v2; } pk;
#pragma unroll
      for (int j=0;j<4;j++) pk.u[j] = f2bf(fmaxf(acc[px][k][j], 0.f));
      *(uint2*)(p + k*4) = pk.v2;
    }
  }
}

// ---------------- dt2 GEMM: cols[p][48] = in[p][128ch] . Wb[48][128]^T, MFMA, no LDS ----------------
__global__ __launch_bounds__(256) void dt2_gemm(
    const u16* __restrict__ inI, const u16* __restrict__ Wb,
    float* __restrict__ cols)
{
  const int tid = threadIdx.x;
  const int w = tid >> 6, lane = tid & 63, quad = lane >> 4, l16 = lane & 15;
  const int pixBase = blockIdx.x*256 + w*64;

  short8 Bf[3][4];
#pragma unroll
  for (int nt=0; nt<3; nt++)
#pragma unroll
    for (int kc=0; kc<4; kc++)
      Bf[nt][kc] = *(const short8*)(Wb + (nt*16 + l16)*128 + kc*32 + quad*8);

  const u16* ap[4];
#pragma unroll
  for (int ms=0; ms<4; ms++) {
    int p = pixBase + ms*16 + l16;
    int b = p >> 14, rem = p & 16383;
    ap[ms] = inI + b*IS130 + (rem >> 7)*RS130 + (rem & 127)*128;
  }

  floatx4 zz = {0.f,0.f,0.f,0.f};
  floatx4 acc[4][3];
#pragma unroll
  for (int ms=0; ms<4; ms++)
#pragma unroll
    for (int nt=0; nt<3; nt++) acc[ms][nt] = zz;

#pragma unroll
  for (int kc=0; kc<4; kc++) {
#pragma unroll
    for (int ms=0; ms<4; ms++) {
      short8 a = *(const short8*)(ap[ms] + kc*32 + quad*8);
#pragma unroll
      for (int nt=0; nt<3; nt++)
        acc[ms][nt] = __builtin_amdgcn_mfma_f32_16x16x32_bf16(a, Bf[nt][kc], acc[ms][nt], 0, 0, 0);
    }
  }

#pragma unroll
  for (int ms=0; ms<4; ms++)
#pragma unroll
    for (int nt=0; nt<3; nt++)
#pragma unroll
      for (int r=0; r<4; r++) {
        int p = pixBase + ms*16 + quad*4 + r;
        cols[(size_t)p*48 + nt*16 + l16] = acc[ms][nt][r];
      }
}

// ---------------- dt2 gather: col2im + bias -> NCHW fp32 ----------------
__global__ __launch_bounds__(256) void dt2_gather(
    const float* __restrict__ cols, const float* __restrict__ bias,
    float* __restrict__ xhat)
{
  int id = blockIdx.x*256 + threadIdx.x;
  int b = id >> 16, rem = id & 65535;
  int ho = rem >> 8, wo = rem & 255;
  const int ph = ho & 1, pw = wo & 1;
  const int hi0 = ph ? ((ho+1)>>1) : (ho>>1);
  const int kh0 = ph ? 0 : 1;
  const int wi0 = pw ? ((wo+1)>>1) : (wo>>1);
  const int kw0 = pw ? 0 : 1;
  float a0 = bias[0], a1 = bias[1], a2 = bias[2];
#pragma unroll
  for (int th=0; th<2; th++) {
    const int hi = hi0 - th;
    if ((unsigned)hi >= 128u) continue;
    const int kh = kh0 + 2*th;
#pragma unroll
    for (int tw=0; tw<2; tw++) {
      const int wi = wi0 - tw;
      if ((unsigned)wi >= 128u) continue;
      const int kw = kw0 + 2*tw;
      const float* r = cols + (size_t)((b << 14) + (hi << 7) + wi)*48 + (kh*4 + kw);
      a0 += r[0]; a1 += r[16]; a2 += r[32];
    }
  }
  const int ob = ((b*3) << 16) + (ho << 8) + wo;
  xhat[ob]          = a0;
  xhat[ob + 65536]  = a1;
  xhat[ob + 131072] = a2;
}

// =====================================================================================
extern "C" void kernel_launch(void* const* d_in, const int* in_sizes, int n_in,
                              void* d_out, int out_size, void* d_ws, size_t ws_size,
                              hipStream_t stream)
{
  const float* x     = (const float*)d_in[0];
  const float* e1w   = (const float*)d_in[1];
  const float* e1b   = (const float*)d_in[2];
  const float* e2w   = (const float*)d_in[3];
  const float* e2b   = (const float*)d_in[4];
  const float* e3w   = (const float*)d_in[5];
  const float* e3b   = (const float*)d_in[6];
  const float* er1aw = (const float*)d_in[7];
  const float* er1ab = (const float*)d_in[8];
  const float* er1bw = (const float*)d_in[9];
  const float* er1bb = (const float*)d_in[10];
  const float* er2aw = (const float*)d_in[11];
  const float* er2ab = (const float*)d_in[12];
  const float* er2bw = (const float*)d_in[13];
  const float* er2bb = (const float*)d_in[14];
  const float* cb    = (const float*)d_in[15];
  const float* d1w   = (const float*)d_in[16];
  const float* d1b   = (const float*)d_in[17];
  const float* dr1aw = (const float*)d_in[18];
  const float* dr1ab = (const float*)d_in[19];
  const float* dr1bw = (const float*)d_in[20];
  const float* dr1bb = (const float*)d_in[21];
  const float* dr2aw = (const float*)d_in[22];
  const float* dr2ab = (const float*)d_in[23];
  const float* dr2bw = (const float*)d_in[24];
  const float* dr2bb = (const float*)d_in[25];
  const float* dt1w  = (const float*)d_in[26];
  const float* dt1b  = (const float*)d_in[27];
  const float* dt2w  = (const float*)d_in[28];
  const float* dt2b  = (const float*)d_in[29];
  float* out = (float*)d_out;

  char* ws = (char*)d_ws;
  size_t off = 0;
  auto alloc = [&](size_t bytes) -> void* {
    void* r = ws + off; off += (bytes + 255) & ~(size_t)255; return r;
  };

  u16* BIG = (u16*)alloc((size_t)IS130*16*2);      // e1-out / ze-compact / dt1-out
  u16* S[4];
  for (int i=0;i<4;i++) S[i] = (u16*)alloc((size_t)IS66*16*2);
  unsigned long long* minb = (unsigned long long*)alloc((size_t)65536*8);
  u16* W_e2 = (u16*)alloc(262144*2);
  u16* W9[6]; for (int i=0;i<6;i++) W9[i] = (u16*)alloc(147456*2);
  u16* W1[4]; for (int i=0;i<4;i++) W1[i] = (u16*)alloc(16384*2);
  u16* Wdt1 = (u16*)alloc(262144*2);
  u16* cbBF = (u16*)alloc(65536*2);
  float* cbn = (float*)alloc(512*4);
  float* wsE1 = (float*)alloc(6144*4);
  u16* Wb48 = (u16*)alloc(6144*2);

  u16* BIGi = BIG + RS130 + 128;
  u16* Si[4];
  for (int i=0;i<4;i++) Si[i] = S[i] + RS66 + 128;
  u16* zeBFc = S[1];            // compact bf16 ze (VQ A-matrix), S1 dead by er2b
  float* zeFc = (float*)BIG;    // compact fp32 ze (32MB) — BIG free between e2 and dt1
  float* cols = (float*)S[1];   // dt2 cols fp32 spans S1..S3 (dead by dt2 time)

  // 1. zero halos + init minb
  zero_halos<<<1812, 256, 0, stream>>>(BIG, S[0], S[1], S[2], S[3], minb);

  // 2. weights
  WTab wtab; int ne = 0; wtab.cum[0] = 0;
  auto addw = [&](const float* s, u16* d, int O, int I, int T, int m, int items) {
    wtab.e[ne] = {s, d, O, I, T, m};
    wtab.cum[ne+1] = wtab.cum[ne] + items; ne++;
  };
  addw(e2w,   W_e2, 128,128,16,0, 262144);
  addw(e3w,   W9[0],128,128, 9,0, 147456);
  addw(er1aw, W9[1],128,128, 9,0, 147456);
  addw(er2aw, W9[2],128,128, 9,0, 147456);
  addw(d1w,   W9[3],128,128, 9,0, 147456);
  addw(dr1aw, W9[4],128,128, 9,0, 147456);
  addw(dr2aw, W9[5],128,128, 9,0, 147456);
  addw(er1bw, W1[0],128,128, 1,0, 16384);
  addw(er2bw, W1[1],128,128, 1,0, 16384);
  addw(dr1bw, W1[2],128,128, 1,0, 16384);
  addw(dr2bw, W1[3],128,128, 1,0, 16384);
  addw(dt1w,  Wdt1, 0,0,0,1, 262144);
  addw(cb,    cbBF, 0,0,0,2, 65536);
  addw(cb,    (u16*)cbn, 0,0,0,3, 512);
  addw(e1w,   (u16*)wsE1, 0,0,0,4, 6144);
  addw(dt2w,  Wb48, 0,0,0,5, 6144);
  wtab.n = ne;
  prep_w<<<(wtab.cum[ne] + 255)/256, 256, 0, stream>>>(wtab);

  // 3. e1
  conv_e1<<<2048, 256, 0, stream>>>(x, wsE1, e1b, BIGi);

  // taps
  Taps t16; t16.n = 16; t16.dh2 = 0; t16.dw2 = 0;
  for (int t=0;t<16;t++) { t16.dh2 |= (unsigned)(t>>2) << (2*t); t16.dw2 |= (unsigned)(t&3) << (2*t); }
  Taps t9; t9.n = 9; t9.dh2 = 0; t9.dw2 = 0;
  for (int t=0;t<9;t++) { t9.dh2 |= (unsigned)(t/3) << (2*t); t9.dw2 |= (unsigned)(t%3) << (2*t); }
  Taps t1x; t1x.n = 1; t1x.dh2 = 1; t1x.dw2 = 1;
  Taps tcm; tcm.n = 4; tcm.dh2 = 0; tcm.dw2 = 0;   // packed: 8 bits per class
  for (int cls=0; cls<4; ++cls) {
    int po = cls >> 1, pw = cls & 1;
    for (int tt=0; tt<4; ++tt) {
      int th = tt >> 1, tw = tt & 1;
      int dh = po ? (th ? 0 : 1) : (th ? -1 : 0);
      int dw = pw ? (tw ? 0 : 1) : (tw ? -1 : 0);
      tcm.dh2 |= (unsigned)(dh+1) << (8*cls + 2*tt);
      tcm.dw2 |= (unsigned)(dw+1) << (8*cls + 2*tt);
    }
  }

  auto conv = [&](const u16* in_, int iRS, int iIS, int si,
                  const u16* w_, const float* b_, Taps tp,
                  u16* o_, int oRS, int oIS, int so, int oh, int ow,
                  const u16* r_, u16* o2, int rl, float* zf, u16* zb) {
    conv_mfma<<<512, 256, 0, stream>>>(in_, iRS, iIS, si, w_, b_, tp,
                                       o_, oRS, oIS, so, oh, ow, r_, o2, rl, zf, zb, 0);
  };

  // encoder
  conv(BIGi, RS130, IS130, 2, W_e2, e2b, t16, Si[0], RS66, IS66, 1,0,0, nullptr, nullptr, 1, nullptr, nullptr); // e2 -> S0 (relu)
  conv(Si[0], RS66, IS66, 1, W9[0], e3b, t9, Si[1], RS66, IS66, 1,0,0, nullptr, Si[2], 0, nullptr, nullptr);    // e3 -> t2=S1, relu->S2
  conv(Si[2], RS66, IS66, 1, W9[1], er1ab, t9, Si[0], RS66, IS66, 1,0,0, nullptr, nullptr, 1, nullptr, nullptr);// er1a -> S0 (relu)
  conv(Si[0], RS66, IS66, 1, W1[0], er1bb, t1x, Si[3], RS66, IS66, 1,0,0, Si[1], Si[2], 0, nullptr, nullptr);   // er1b(+t2) -> t4=S3, relu->S2
  conv(Si[2], RS66, IS66, 1, W9[2], er2ab, t9, Si[0], RS66, IS66, 1,0,0, nullptr, nullptr, 1, nullptr, nullptr);// er2a -> S0 (relu)
  conv(Si[0], RS66, IS66, 1, W1[1], er2bb, t1x, nullptr, RS66, IS66, 1,0,0, Si[3], nullptr, 0, zeFc, zeBFc);    // er2b(+t4) -> ze compact (fp32+bf16)

  // VQ + outputs
  vq_score<<<dim3(512,4), 256, 0, stream>>>(zeBFc, cbBF, cbn, minb);
  finalize<<<1024, 256, 0, stream>>>(zeFc, minb, cb, out + 3145728, out + 11534336, Si[2]);  // zq bf16 -> S2

  // decoder
  conv(Si[2], RS66, IS66, 1, W9[3], d1b, t9, Si[0], RS66, IS66, 1,0,0, nullptr, Si[1], 0, nullptr, nullptr);    // d1 -> g1=S0, relu->S1
  conv(Si[1], RS66, IS66, 1, W9[4], dr1ab, t9, Si[2], RS66, IS66, 1,0,0, nullptr, nullptr, 1, nullptr, nullptr);// dr1a -> S2 (relu)
  conv(Si[2], RS66, IS66, 1, W1[2], dr1bb, t1x, Si[3], RS66, IS66, 1,0,0, Si[0], Si[1], 0, nullptr, nullptr);   // dr1b(+g1) -> g2=S3, relu->S1
  conv(Si[1], RS66, IS66, 1, W9[5], dr2ab, t9, Si[2], RS66, IS66, 1,0,0, nullptr, nullptr, 1, nullptr, nullptr);// dr2a -> S2 (relu)
  conv(Si[2], RS66, IS66, 1, W1[3], dr2bb, t1x, Si[0], RS66, IS66, 1,0,0, Si[3], nullptr, 0, nullptr, nullptr); // dr2b(+g2) -> g3=S0

  // dt1: 4 parity classes in one dispatch (blockIdx.y = cls)
  conv_mfma<<<dim3(512,4), 256, 0, stream>>>(Si[0], RS66, IS66, 1, Wdt1, dt1b, tcm,
                                             BIGi, RS130, IS130, 2, 0, 0,
                                             nullptr, nullptr, 1, nullptr, nullptr, 1);

  // dt2: cols GEMM (MFMA) + col2im gather
  dt2_gemm<<<1024, 256, 0, stream>>>(BIGi, Wb48, cols);
  dt2_gather<<<4096, 256, 0, stream>>>(cols, dt2b, out);
}